// Round 3
// baseline (183.916 us; speedup 1.0000x reference)
//
#include <hip/hip_runtime.h>
#include <math.h>

#define BB 8
#define DD 768
#define HWN 1024
#define CC 2
#define NS 256      // sampled sites (16x16)
#define KOFF 12
#define PPAD 3072   // NS*KOFF padded pairs per (b,c)
#define O1 256
#define O2 128

// site offsets in sample-grid units (pixel Manhattan dist = 2*(|du|+|dv|) in {2,4})
__constant__ int c_du[12] = {1,-1,0,0,2,-2,0,0,1, 1,-1,-1};
__constant__ int c_dv[12] = {0, 0,1,-1,0, 0,2,-2,1,-1, 1,-1};

// ---------------- pooling + site gather ----------------
// block = (b*768+d) row of 1024, 256 threads (float4 each)
__global__ void __launch_bounds__(256) k_pool(const float* __restrict__ feat,
                                              float* __restrict__ fg,
                                              float* __restrict__ g) {
  int row = blockIdx.x;                 // b*D + d
  int t = threadIdx.x;
  const float4 v = reinterpret_cast<const float4*>(feat + (size_t)row * HWN)[t];
  float s = v.x + v.y + v.z + v.w;
#pragma unroll
  for (int m = 32; m >= 1; m >>= 1) s += __shfl_xor(s, m, 64);
  __shared__ float red[4];
  if ((t & 63) == 0) red[t >> 6] = s;
  // gather sampled sites: thread t covers pix 4t..4t+3; sampled rows need bit3(t)==0
  if ((t & 8) == 0) {
    int b = row / DD, d = row - b * DD;
    int u = t >> 4, r = t & 7;
    int s1 = u * 16 + 2 * r;            // pix 64u+4r   -> v.x
    g[((size_t)(b * NS + s1)) * DD + d] = v.x;
    g[((size_t)(b * NS + s1 + 1)) * DD + d] = v.z;   // pix 64u+4r+2
  }
  __syncthreads();
  if (t == 0) fg[row] = (red[0] + red[1] + red[2] + red[3]) * (1.0f / 1024.0f);
}

// ---------------- z posterior MLPs ----------------
__global__ void __launch_bounds__(256) k_zmlp(const float* __restrict__ fg,
    const float* __restrict__ muW1, const float* __restrict__ mub1,
    const float* __restrict__ muW2, const float* __restrict__ mub2,
    const float* __restrict__ lsW1, const float* __restrict__ lsb1,
    const float* __restrict__ lsW2, const float* __restrict__ lsb2,
    const float* __restrict__ eps,
    float* __restrict__ o_zmu, float* __restrict__ o_zls, float* __restrict__ o_zs) {
  int b = blockIdx.x;
  int t = threadIdx.x;
  __shared__ float sf[DD];
  __shared__ float shm[256], shl[256];
  for (int i = t; i < DD; i += 256) sf[i] = fg[b * DD + i];
  __syncthreads();
  float hmu = mub1[t], hls = lsb1[t];
  for (int d = 0; d < DD; d++) {
    float f = sf[d];
    hmu = fmaf(f, muW1[d * 256 + t], hmu);
    hls = fmaf(f, lsW1[d * 256 + t], hls);
  }
  shm[t] = fmaxf(hmu, 0.f);
  shl[t] = fmaxf(hls, 0.f);
  __syncthreads();
  if (t < 8) {
    float zm = mub2[t], zl = lsb2[t];
    for (int i = 0; i < 256; i++) {
      zm = fmaf(shm[i], muW2[i * 8 + t], zm);
      zl = fmaf(shl[i], lsW2[i * 8 + t], zl);
    }
    o_zmu[b * 8 + t] = zm;
    o_zls[b * 8 + t] = zl;
    o_zs[b * 8 + t] = zm + expf(zl) * eps[b * 8 + t];
  }
}

// ---------------- EH = 0.5*(coord_emb[site] @ W1_bot + b1) ----------------
__global__ void __launch_bounds__(256) k_EH(const float* __restrict__ cemb,
                                            const float* __restrict__ W1,
                                            const float* __restrict__ b1,
                                            float* __restrict__ EH) {
  int bs = blockIdx.x;                  // c*256+s
  int c = bs >> 8, s = bs & 255;
  int u = s >> 4, v = s & 15;
  int pix = (u << 6) + (v << 1);
  __shared__ float ce[128];
  int t = threadIdx.x;
  if (t < 128) ce[t] = cemb[(size_t)pix * 128 + t];
  __syncthreads();
  const float* W = W1 + ((size_t)c * 1664 + 1536) * O1;
  float acc = 0.f;
  for (int e = 0; e < 128; e++) acc = fmaf(ce[e], W[(size_t)e * O1 + t], acc);
  EH[((size_t)(c * NS + s)) * O1 + t] = 0.5f * (acc + b1[c * O1 + t]);
}

// ---------------- site projection GEMM: Gbuf[ch][2048][256] ----------------
// ch = half*2 + c ; rows = b*256+s over gathered g[2048][768]
__global__ void __launch_bounds__(256) k_gemm(const float* __restrict__ g,
                                              const float* __restrict__ W1,
                                              float* __restrict__ Gbuf) {
  int rt = blockIdx.x;        // 0..31 (64-row tiles)
  int ct = blockIdx.y;        // 0..3  (64-col tiles)
  int ch = blockIdx.z;        // 0..3 : c = ch&1, half = ch>>1
  int c = ch & 1, half = ch >> 1;
  const float* Wb = W1 + ((size_t)c * 1664 + (size_t)half * 768) * O1;
  int t = threadIdx.x;
  int tx = t & 15, ty = t >> 4;
  __shared__ __align__(16) float As[16][68];
  __shared__ __align__(16) float Bs[16][64];
  float acc[4][4];
#pragma unroll
  for (int i = 0; i < 4; i++)
#pragma unroll
    for (int j = 0; j < 4; j++) acc[i][j] = 0.f;
  int row0 = rt * 64, col0 = ct * 64;
  for (int k0 = 0; k0 < DD; k0 += 16) {
    {
      int rl = t >> 2, kq = (t & 3) * 4;
      float4 a = *reinterpret_cast<const float4*>(&g[((size_t)(row0 + rl)) * DD + k0 + kq]);
      As[kq + 0][rl] = a.x; As[kq + 1][rl] = a.y; As[kq + 2][rl] = a.z; As[kq + 3][rl] = a.w;
    }
    {
      int kl = t >> 4, o4 = (t & 15) * 4;
      *reinterpret_cast<float4*>(&Bs[kl][o4]) =
          *reinterpret_cast<const float4*>(&Wb[(size_t)(k0 + kl) * O1 + col0 + o4]);
    }
    __syncthreads();
#pragma unroll
    for (int kk = 0; kk < 16; kk++) {
      float4 a = *reinterpret_cast<float4*>(&As[kk][ty * 4]);
      float4 b = *reinterpret_cast<float4*>(&Bs[kk][tx * 4]);
      float av[4] = {a.x, a.y, a.z, a.w};
      float bv[4] = {b.x, b.y, b.z, b.w};
#pragma unroll
      for (int i = 0; i < 4; i++)
#pragma unroll
        for (int j = 0; j < 4; j++) acc[i][j] = fmaf(av[i], bv[j], acc[i][j]);
    }
    __syncthreads();
  }
#pragma unroll
  for (int i = 0; i < 4; i++) {
    float4 o = make_float4(acc[i][0], acc[i][1], acc[i][2], acc[i][3]);
    *reinterpret_cast<float4*>(&Gbuf[((size_t)ch * 2048 + row0 + ty * 4 + i) * O1 + col0 + tx * 4]) = o;
  }
}

// ---------------- pair MLP (layers 2+3 fused, layer1 = gather-adds) ----------------
// block: (b,c, group of 64 padded pairs); 512 threads: tx=t&31 (4 cols), py=t>>5 (4 pairs)
__global__ void __launch_bounds__(512) k_pairmlp(const float* __restrict__ Gbuf,
    const float* __restrict__ EH,
    const float* __restrict__ W2, const float* __restrict__ b2,
    const float* __restrict__ W3, const float* __restrict__ b3,
    float* __restrict__ val) {
  int blk = blockIdx.x;               // 16*48
  int bc = blk / 48, grp = blk - bc * 48;
  int b = bc >> 1, c = bc & 1;
  int t = threadIdx.x;
  int tx = t & 31, py = t >> 5;
  __shared__ __align__(16) float h1T[32][68];
  __shared__ __align__(16) float Ws[32][128];
  float acc[4][4];
#pragma unroll
  for (int i = 0; i < 4; i++)
#pragma unroll
    for (int j = 0; j < 4; j++) acc[i][j] = 0.f;
  const float* W2c = W2 + (size_t)c * O1 * O2;
  // staging metadata (this thread stages pair p_l, i-range iq..iq+3 each chunk)
  int p_l = t >> 3, iq = (t & 7) * 4;
  int j = grp * 64 + p_l;
  int s = j / 12, k = j - s * 12;
  int u = s >> 4, v = s & 15;
  int ub = u + c_du[k], vb = v + c_dv[k];
  bool valid = (ub >= 0) && (ub < 16) && (vb >= 0) && (vb < 16);
  int sb = valid ? ub * 16 + vb : s;
  const float* g1p = Gbuf + ((size_t)(c * 2048 + b * NS + s)) * O1;
  const float* g2p = Gbuf + ((size_t)((2 + c) * 2048 + b * NS + sb)) * O1;
  const float* eap = EH + ((size_t)(c * NS + s)) * O1;
  const float* ebp = EH + ((size_t)(c * NS + sb)) * O1;

  for (int i0 = 0; i0 < O1; i0 += 32) {
    {
      float4 a1 = *reinterpret_cast<const float4*>(g1p + i0 + iq);
      float4 a2 = *reinterpret_cast<const float4*>(g2p + i0 + iq);
      float4 e1 = *reinterpret_cast<const float4*>(eap + i0 + iq);
      float4 e2 = *reinterpret_cast<const float4*>(ebp + i0 + iq);
      h1T[iq + 0][p_l] = fmaxf(a1.x + a2.x + e1.x + e2.x, 0.f);
      h1T[iq + 1][p_l] = fmaxf(a1.y + a2.y + e1.y + e2.y, 0.f);
      h1T[iq + 2][p_l] = fmaxf(a1.z + a2.z + e1.z + e2.z, 0.f);
      h1T[iq + 3][p_l] = fmaxf(a1.w + a2.w + e1.w + e2.w, 0.f);
    }
    {
      int il = t >> 4, o8 = (t & 15) * 8;
      const float* wp = W2c + (size_t)(i0 + il) * O2 + o8;
      *reinterpret_cast<float4*>(&Ws[il][o8]) = *reinterpret_cast<const float4*>(wp);
      *reinterpret_cast<float4*>(&Ws[il][o8 + 4]) = *reinterpret_cast<const float4*>(wp + 4);
    }
    __syncthreads();
#pragma unroll
    for (int i = 0; i < 32; i++) {
      float4 a = *reinterpret_cast<float4*>(&h1T[i][py * 4]);
      float4 w = *reinterpret_cast<float4*>(&Ws[i][tx * 4]);
      float av[4] = {a.x, a.y, a.z, a.w};
      float wv[4] = {w.x, w.y, w.z, w.w};
#pragma unroll
      for (int pp = 0; pp < 4; pp++)
#pragma unroll
        for (int ccx = 0; ccx < 4; ccx++) acc[pp][ccx] = fmaf(av[pp], wv[ccx], acc[pp][ccx]);
    }
    __syncthreads();
  }
  // epilogue: + b2, relu, dot with W3 over this thread's 4 cols, reduce over tx (32 lanes)
  float4 b2v = *reinterpret_cast<const float4*>(&b2[c * O2 + tx * 4]);
  float4 w3v = *reinterpret_cast<const float4*>(&W3[c * O2 + tx * 4]);
  float b3v = b3[c];
  float part[4];
#pragma unroll
  for (int pp = 0; pp < 4; pp++) {
    float h0 = fmaxf(acc[pp][0] + b2v.x, 0.f);
    float h1 = fmaxf(acc[pp][1] + b2v.y, 0.f);
    float h2 = fmaxf(acc[pp][2] + b2v.z, 0.f);
    float h3 = fmaxf(acc[pp][3] + b2v.w, 0.f);
    part[pp] = h0 * w3v.x + h1 * w3v.y + h2 * w3v.z + h3 * w3v.w;
  }
#pragma unroll
  for (int m = 16; m >= 1; m >>= 1) {
#pragma unroll
    for (int pp = 0; pp < 4; pp++) part[pp] += __shfl_xor(part[pp], m, 64);
  }
  if (tx == 0) {
#pragma unroll
    for (int pp = 0; pp < 4; pp++) {
      int jj = grp * 64 + py * 4 + pp;
      int ss = jj / 12, kk2 = jj - ss * 12;
      int uu = ss >> 4, vv2 = ss & 15;
      int ub2 = uu + c_du[kk2], vb2 = vv2 + c_dv[kk2];
      bool vld = (ub2 >= 0) && (ub2 < 16) && (vb2 >= 0) && (vb2 < 16);
      float lg = part[pp] + b3v;
      float sv = 1.0f / (1.0f + expf(-lg));
      val[(size_t)bc * PPAD + jj] = vld ? sv : 0.0f;
    }
  }
}

// ---------------- row sums S = 1 + sum_k val ----------------
__global__ void __launch_bounds__(256) k_rowsum(const float* __restrict__ val,
                                                float* __restrict__ S) {
  int i = blockIdx.x * 256 + threadIdx.x;     // (b*2+c)*256+s, 4096 total
  float s = 1.0f;
  const float* v = val + (size_t)i * 12;
#pragma unroll
  for (int k = 0; k < 12; k++) s += v[k];
  S[i] = s;
}

// ---------------- scatter A (A pre-zeroed by memset) ----------------
__global__ void __launch_bounds__(256) k_scatter(const float* __restrict__ val,
                                                 const float* __restrict__ S,
                                                 float* __restrict__ A) {
  int idx = blockIdx.x * 256 + threadIdx.x;   // 16384 rows total
  int row = idx & 1023;
  int bc = idx >> 10;
  size_t base = (size_t)bc * HWN * HWN + (size_t)row * HWN;
  int pi = row >> 5, pj = row & 31;
  if (((pi & 1) == 0) && ((pj & 1) == 0)) {
    int u = pi >> 1, v = pj >> 1;
    int s = u * 16 + v;
    float Sv = S[bc * NS + s];
    float inv = 1.0f / (Sv + 1e-8f);
    A[base + row] = inv;
#pragma unroll
    for (int k = 0; k < 12; k++) {
      int ub = u + c_du[k], vb = v + c_dv[k];
      if (ub >= 0 && ub < 16 && vb >= 0 && vb < 16) {
        int colpix = (ub << 6) + (vb << 1);
        A[base + colpix] = val[(size_t)bc * PPAD + s * 12 + k] * inv;
      }
    }
  } else {
    A[base + row] = 1.0f / (1.0f + 1e-8f);
  }
}

// ---------------- sparse diffusion + cam/conf outputs ----------------
__global__ void __launch_bounds__(256) k_diffuse(const float* __restrict__ cam,
    const float* __restrict__ val, const float* __restrict__ S,
    const float* __restrict__ csc, const float* __restrict__ cbi,
    float* __restrict__ o_cam, float* __restrict__ o_conf) {
  int bc = blockIdx.x;
  int t = threadIdx.x;                 // = site s
  __shared__ float M[NS];
  int u = t >> 4, v = t & 15;
  int pix = (u << 6) + (v << 1);
  const float* camr = cam + (size_t)bc * HWN;
  float m = camr[pix];
  float Sv = S[bc * NS + t];
  float inv = 1.0f / (Sv + 1e-8f);
  float degn = Sv * inv;
  float vv[12];
  int nb[12];
#pragma unroll
  for (int k = 0; k < 12; k++) {
    int ub = u + c_du[k], vb = v + c_dv[k];
    bool vld = (ub >= 0) && (ub < 16) && (vb >= 0) && (vb < 16);
    nb[k] = vld ? ub * 16 + vb : t;
    vv[k] = vld ? val[(size_t)bc * PPAD + t * 12 + k] : 0.0f;
  }
  M[t] = m;
  __syncthreads();
  for (int step = 0; step < 3; step++) {
    float accv = m;
#pragma unroll
    for (int k = 0; k < 12; k++) accv = fmaf(vv[k], M[nb[k]], accv);
    float L = accv * inv - degn * m;
    m = fmaf(0.1f, L, m);
    __syncthreads();
    M[t] = m;
    __syncthreads();
  }
  float scale = csc[0], bias = cbi[0];
  for (int p = t; p < HWN; p += 256) {
    int pi = p >> 5, pj = p & 31;
    float x;
    if (((pi & 1) == 0) && ((pj & 1) == 0)) x = M[(pi >> 1) * 16 + (pj >> 1)];
    else x = camr[p];
    x = fminf(fmaxf(x, 0.0f), 1.0f);
    o_cam[(size_t)bc * HWN + p] = x;
    o_conf[(size_t)bc * HWN + p] = 1.0f / (1.0f + expf(-(scale * x + bias)));
  }
}

extern "C" void kernel_launch(void* const* d_in, const int* in_sizes, int n_in,
                              void* d_out, int out_size, void* d_ws, size_t ws_size,
                              hipStream_t stream) {
  const float* feat = (const float*)d_in[0];
  const float* cam  = (const float*)d_in[1];
  const float* eps  = (const float*)d_in[3];
  const float* cemb = (const float*)d_in[4];
  const float* aW1  = (const float*)d_in[5];
  const float* ab1  = (const float*)d_in[6];
  const float* aW2  = (const float*)d_in[7];
  const float* ab2  = (const float*)d_in[8];
  const float* aW3  = (const float*)d_in[9];
  const float* ab3  = (const float*)d_in[10];
  const float* muW1 = (const float*)d_in[11];
  const float* mub1 = (const float*)d_in[12];
  const float* muW2 = (const float*)d_in[13];
  const float* mub2 = (const float*)d_in[14];
  const float* lsW1 = (const float*)d_in[15];
  const float* lsb1 = (const float*)d_in[16];
  const float* lsW2 = (const float*)d_in[17];
  const float* lsb2 = (const float*)d_in[18];
  const float* csc  = (const float*)d_in[19];
  const float* cbi  = (const float*)d_in[20];

  float* out = (float*)d_out;
  float* o_cam  = out;                       // 16384
  float* o_zmu  = out + 16384;               // 64
  float* o_zls  = out + 16448;               // 64
  float* o_zs   = out + 16512;               // 64
  float* o_A    = out + 16576;               // 16777216
  float* o_conf = out + 16793792;            // 16384

  // big scratch lives in the (not-yet-written) A output region; only val/S in d_ws
  float* fg   = o_A;                         // 6144
  float* g    = o_A + 6144;                  // 1572864
  float* Gbuf = o_A + 1579008;               // 2097152  (4 chunks of 2048x256)
  float* EHb  = o_A + 3676160;               // 131072
  float* valb = (float*)d_ws;                // 49152
  float* Sb   = valb + PPAD * 16;            // 4096

  hipLaunchKernelGGL(k_pool, dim3(BB * DD), dim3(256), 0, stream, feat, fg, g);
  hipLaunchKernelGGL(k_zmlp, dim3(BB), dim3(256), 0, stream, fg, muW1, mub1, muW2,
                     mub2, lsW1, lsb1, lsW2, lsb2, eps, o_zmu, o_zls, o_zs);
  hipLaunchKernelGGL(k_EH, dim3(512), dim3(256), 0, stream, cemb, aW1, ab1, EHb);
  hipLaunchKernelGGL(k_gemm, dim3(32, 4, 4), dim3(256), 0, stream, g, aW1, Gbuf);
  hipLaunchKernelGGL(k_pairmlp, dim3(768), dim3(512), 0, stream, Gbuf, EHb, aW2,
                     ab2, aW3, ab3, valb);
  hipLaunchKernelGGL(k_rowsum, dim3(16), dim3(256), 0, stream, valb, Sb);
  hipMemsetAsync(o_A, 0, (size_t)16777216 * 4, stream);
  hipLaunchKernelGGL(k_scatter, dim3(64), dim3(256), 0, stream, valb, Sb, o_A);
  hipLaunchKernelGGL(k_diffuse, dim3(16), dim3(256), 0, stream, cam, valb, Sb,
                     csc, cbi, o_cam, o_conf);
}

// Round 4
// 128.448 us; speedup vs baseline: 1.4318x; 1.4318x over previous
//
#include <hip/hip_runtime.h>
#include <math.h>

#define BB 8
#define DD 768
#define HWN 1024
#define NS 256
#define PPAD 3072
#define O1 256
#define O2 128

typedef __attribute__((ext_vector_type(8))) short bf16x8;
typedef __attribute__((ext_vector_type(4))) float f32x4;

__constant__ int c_du[12] = {1,-1,0,0,2,-2,0,0,1, 1,-1,-1};
__constant__ int c_dv[12] = {0, 0,1,-1,0, 0,2,-2,1,-1, 1,-1};
// reverse map (du+2)*5+(dv+2) -> offset index k (-1 = not a neighbor)
__constant__ signed char c_rk[25] = {
  -1,-1, 5,-1,-1,
  -1,11, 1,10,-1,
   7, 3,-1, 2, 6,
  -1, 9, 0, 8,-1,
  -1,-1, 4,-1,-1};

__device__ inline ushort f2bf(float x) {
  unsigned u = __float_as_uint(x);
  u += 0x7FFF + ((u >> 16) & 1);
  return (ushort)(u >> 16);
}
__device__ inline float bf2f(ushort h) { return __uint_as_float(((unsigned)h) << 16); }

// ---------------- pooling + site gather (g now bf16) ----------------
__global__ void __launch_bounds__(256) k_pool(const float* __restrict__ feat,
                                              float* __restrict__ fg,
                                              ushort* __restrict__ g16) {
  int row = blockIdx.x;                 // b*D + d
  int t = threadIdx.x;
  const float4 v = reinterpret_cast<const float4*>(feat + (size_t)row * HWN)[t];
  float s = v.x + v.y + v.z + v.w;
#pragma unroll
  for (int m = 32; m >= 1; m >>= 1) s += __shfl_xor(s, m, 64);
  __shared__ float red[4];
  if ((t & 63) == 0) red[t >> 6] = s;
  if ((t & 8) == 0) {
    int b = row / DD, d = row - b * DD;
    int u = t >> 4, r = t & 7;
    int s1 = u * 16 + 2 * r;
    g16[((size_t)(b * NS + s1)) * DD + d] = f2bf(v.x);
    g16[((size_t)(b * NS + s1 + 1)) * DD + d] = f2bf(v.z);
  }
  __syncthreads();
  if (t == 0) fg[row] = (red[0] + red[1] + red[2] + red[3]) * (1.0f / 1024.0f);
}

// ---------------- z posterior MLPs ----------------
__global__ void __launch_bounds__(256) k_zmlp(const float* __restrict__ fg,
    const float* __restrict__ muW1, const float* __restrict__ mub1,
    const float* __restrict__ muW2, const float* __restrict__ mub2,
    const float* __restrict__ lsW1, const float* __restrict__ lsb1,
    const float* __restrict__ lsW2, const float* __restrict__ lsb2,
    const float* __restrict__ eps,
    float* __restrict__ o_zmu, float* __restrict__ o_zls, float* __restrict__ o_zs) {
  int b = blockIdx.x;
  int t = threadIdx.x;
  __shared__ float sf[DD];
  __shared__ float shm[256], shl[256];
  for (int i = t; i < DD; i += 256) sf[i] = fg[b * DD + i];
  __syncthreads();
  float hmu = mub1[t], hls = lsb1[t];
  for (int d = 0; d < DD; d++) {
    float f = sf[d];
    hmu = fmaf(f, muW1[d * 256 + t], hmu);
    hls = fmaf(f, lsW1[d * 256 + t], hls);
  }
  shm[t] = fmaxf(hmu, 0.f);
  shl[t] = fmaxf(hls, 0.f);
  __syncthreads();
  if (t < 8) {
    float zm = mub2[t], zl = lsb2[t];
    for (int i = 0; i < 256; i++) {
      zm = fmaf(shm[i], muW2[i * 8 + t], zm);
      zl = fmaf(shl[i], lsW2[i * 8 + t], zl);
    }
    o_zmu[b * 8 + t] = zm;
    o_zls[b * 8 + t] = zl;
    o_zs[b * 8 + t] = zm + expf(zl) * eps[b * 8 + t];
  }
}

// ---------------- EH = 0.5*(coord_emb[site] @ W1_bot + b1), f32 ----------------
__global__ void __launch_bounds__(256) k_EH(const float* __restrict__ cemb,
                                            const float* __restrict__ W1,
                                            const float* __restrict__ b1,
                                            float* __restrict__ EH) {
  int bs = blockIdx.x;                  // c*256+s
  int c = bs >> 8, s = bs & 255;
  int u = s >> 4, v = s & 15;
  int pix = (u << 6) + (v << 1);
  __shared__ float ce[128];
  int t = threadIdx.x;
  if (t < 128) ce[t] = cemb[(size_t)pix * 128 + t];
  __syncthreads();
  const float* W = W1 + ((size_t)c * 1664 + 1536) * O1;
  float acc = 0.f;
  for (int e = 0; e < 128; e++) acc = fmaf(ce[e], W[(size_t)e * O1 + t], acc);
  EH[((size_t)(c * NS + s)) * O1 + t] = 0.5f * (acc + b1[c * O1 + t]);
}

// ---------------- transpose W1 (4 slices 768x256) + W2 (2x 256x128) to bf16 [n][k] ----------------
__global__ void __launch_bounds__(256) k_transpose(const float* __restrict__ W1,
    const float* __restrict__ W2, ushort* __restrict__ WT16, ushort* __restrict__ W2T16) {
  int blk = blockIdx.x, t = threadIdx.x;
  const float* src; ushort* dst; int K, N, k0, n0;
  if (blk < 192) {
    int ch = blk / 48, r = blk % 48;
    int c = ch & 1, half = ch >> 1;
    src = W1 + ((size_t)c * 1664 + half * 768) * 256;
    dst = WT16 + (size_t)ch * 256 * 768;
    K = 768; N = 256; k0 = (r >> 2) * 64; n0 = (r & 3) * 64;
  } else {
    int r = blk - 192;
    int c = r >> 3; int q = r & 7;
    src = W2 + (size_t)c * 256 * 128;
    dst = W2T16 + (size_t)c * 128 * 256;
    K = 256; N = 128; k0 = (q >> 1) * 64; n0 = (q & 1) * 64;
  }
  __shared__ float T[64][65];
  for (int i = 0; i < 16; i++) {
    int idx = i * 256 + t; int kl = idx >> 6, nl = idx & 63;
    T[kl][nl] = src[(size_t)(k0 + kl) * N + n0 + nl];
  }
  __syncthreads();
  for (int i = 0; i < 16; i++) {
    int idx = i * 256 + t; int nl = idx >> 6, kl = idx & 63;
    dst[(size_t)(n0 + nl) * K + k0 + kl] = f2bf(T[kl][nl]);
  }
}

// ---------------- MFMA site projection: Fb16[ch][2048][256] = g@W1slice + EH ----------------
__global__ void __launch_bounds__(256) k_gemm_mfma(const ushort* __restrict__ g16,
    const ushort* __restrict__ WT16, const float* __restrict__ EHb,
    ushort* __restrict__ Fb16) {
  int mt = blockIdx.x, nt = blockIdx.y, ch = blockIdx.z;
  int c = ch & 1;
  int row0 = mt * 64, col0 = nt * 64;
  int t = threadIdx.x;
  int wid = t >> 6, l = t & 63;
  int wm = wid & 1, wn = wid >> 1;
  int lm = l & 15, lk = (l >> 4) * 8;
  __shared__ float ehs[64][64];
  int s0 = row0 & 255;
  for (int i = 0; i < 16; i++) {
    int idx = i * 256 + t; int rl = idx >> 6, nl = idx & 63;
    ehs[rl][nl] = EHb[((size_t)(c * 256 + s0 + rl)) * 256 + col0 + nl];
  }
  f32x4 acc[2][2] = {};
  const ushort* ap0 = g16 + (size_t)(row0 + wm * 32 + lm) * DD + lk;
  const ushort* bp0 = WT16 + ((size_t)ch * 256 + col0 + wn * 32 + lm) * DD + lk;
#pragma unroll 4
  for (int k0 = 0; k0 < DD; k0 += 32) {
    bf16x8 a0 = *(const bf16x8*)(ap0 + k0);
    bf16x8 a1 = *(const bf16x8*)(ap0 + 16 * DD + k0);
    bf16x8 b0 = *(const bf16x8*)(bp0 + k0);
    bf16x8 b1 = *(const bf16x8*)(bp0 + 16 * DD + k0);
    acc[0][0] = __builtin_amdgcn_mfma_f32_16x16x32_bf16(a0, b0, acc[0][0], 0, 0, 0);
    acc[0][1] = __builtin_amdgcn_mfma_f32_16x16x32_bf16(a0, b1, acc[0][1], 0, 0, 0);
    acc[1][0] = __builtin_amdgcn_mfma_f32_16x16x32_bf16(a1, b0, acc[1][0], 0, 0, 0);
    acc[1][1] = __builtin_amdgcn_mfma_f32_16x16x32_bf16(a1, b1, acc[1][1], 0, 0, 0);
  }
  __syncthreads();
#pragma unroll
  for (int i = 0; i < 2; i++)
#pragma unroll
    for (int jj = 0; jj < 2; jj++)
#pragma unroll
      for (int r = 0; r < 4; r++) {
        int rm = wm * 32 + i * 16 + (l >> 4) * 4 + r;
        int cn = wn * 32 + jj * 16 + lm;
        float vo = acc[i][jj][r] + ehs[rm][cn];
        Fb16[((size_t)ch * 2048 + row0 + rm) * 256 + col0 + cn] = f2bf(vo);
      }
}

// ---------------- MFMA pair MLP: h1 = relu(F1[sa]+F2[sb]); layers 2+3 fused ----------------
__global__ void __launch_bounds__(256) k_pairmlp_mfma(const ushort* __restrict__ Fb16,
    const ushort* __restrict__ W2T16, const float* __restrict__ b2,
    const float* __restrict__ W3, const float* __restrict__ b3,
    float* __restrict__ val) {
  int blk = blockIdx.x;
  int bc = blk / 48, grp = blk - bc * 48;
  int b = bc >> 1, c = bc & 1;
  int t = threadIdx.x;
  int wid = t >> 6, l = t & 63;
  int wm = wid & 1, wn = wid >> 1;
  int lm = l & 15, lk = (l >> 4) * 8;
  __shared__ ushort h1s[64 * 256];     // 32 KB, XOR-swizzled
  __shared__ float psum[2][64];
  {
    int p_l = t >> 2, q = t & 3;
    int j = grp * 64 + p_l;
    int s = j / 12, ko = j - s * 12;
    int u = s >> 4, v = s & 15;
    int ub = u + c_du[ko], vb = v + c_dv[ko];
    bool vld = (ub >= 0) && (ub < 16) && (vb >= 0) && (vb < 16);
    int sb = vld ? ub * 16 + vb : s;
    const ushort* f1p = Fb16 + ((size_t)(c * 2048 + b * 256 + s)) * 256 + q * 64;
    const ushort* f2p = Fb16 + ((size_t)((2 + c) * 2048 + b * 256 + sb)) * 256 + q * 64;
    char* hb = (char*)h1s;
#pragma unroll
    for (int kk = 0; kk < 64; kk += 8) {
      bf16x8 x1 = *(const bf16x8*)(f1p + kk);
      bf16x8 x2 = *(const bf16x8*)(f2p + kk);
      bf16x8 o;
#pragma unroll
      for (int e = 0; e < 8; e++) {
        float a = bf2f((ushort)x1[e]) + bf2f((ushort)x2[e]);
        o[e] = (short)f2bf(fmaxf(a, 0.f));
      }
      int byt = (p_l * 512 + (q * 64 + kk) * 2) ^ ((p_l & 7) << 4);
      *(bf16x8*)(hb + byt) = o;
    }
  }
  __syncthreads();
  f32x4 acc[2][4] = {};
  const ushort* wp = W2T16 + ((size_t)(c * 128 + wn * 64 + lm)) * 256 + lk;
  const char* hb = (const char*)h1s;
  int p0 = wm * 32 + lm;
  int swz = (p0 & 7) << 4;
#pragma unroll 2
  for (int k0 = 0; k0 < 256; k0 += 32) {
    bf16x8 a0 = *(const bf16x8*)(hb + ((p0 * 512 + (k0 + lk) * 2) ^ swz));
    bf16x8 a1 = *(const bf16x8*)(hb + (((p0 + 16) * 512 + (k0 + lk) * 2) ^ swz));
#pragma unroll
    for (int nf = 0; nf < 4; nf++) {
      bf16x8 bb = *(const bf16x8*)(wp + nf * 16 * 256 + k0);
      acc[0][nf] = __builtin_amdgcn_mfma_f32_16x16x32_bf16(a0, bb, acc[0][nf], 0, 0, 0);
      acc[1][nf] = __builtin_amdgcn_mfma_f32_16x16x32_bf16(a1, bb, acc[1][nf], 0, 0, 0);
    }
  }
  float b2v[4], w3v[4];
#pragma unroll
  for (int nf = 0; nf < 4; nf++) {
    int col = wn * 64 + nf * 16 + lm;
    b2v[nf] = b2[c * 128 + col];
    w3v[nf] = W3[c * 128 + col];
  }
  float part[2][4];
#pragma unroll
  for (int mf = 0; mf < 2; mf++)
#pragma unroll
    for (int r = 0; r < 4; r++) {
      float ssum = 0.f;
#pragma unroll
      for (int nf = 0; nf < 4; nf++) {
        float h = fmaxf(acc[mf][nf][r] + b2v[nf], 0.f);
        ssum = fmaf(h, w3v[nf], ssum);
      }
      part[mf][r] = ssum;
    }
#pragma unroll
  for (int m = 1; m <= 8; m <<= 1)
#pragma unroll
    for (int mf = 0; mf < 2; mf++)
#pragma unroll
      for (int r = 0; r < 4; r++)
        part[mf][r] += __shfl_xor(part[mf][r], m, 64);
  if (lm == 0) {
#pragma unroll
    for (int mf = 0; mf < 2; mf++)
#pragma unroll
      for (int r = 0; r < 4; r++)
        psum[wn][wm * 32 + mf * 16 + (l >> 4) * 4 + r] = part[mf][r];
  }
  __syncthreads();
  if (t < 64) {
    int jj = grp * 64 + t;
    int ss = jj / 12, kk2 = jj - ss * 12;
    int uu = ss >> 4, vv2 = ss & 15;
    int ub2 = uu + c_du[kk2], vb2 = vv2 + c_dv[kk2];
    bool vld = (ub2 >= 0) && (ub2 < 16) && (vb2 >= 0) && (vb2 < 16);
    float lg = psum[0][t] + psum[1][t] + b3[c];
    float sv = 1.0f / (1.0f + expf(-lg));
    val[(size_t)bc * PPAD + jj] = vld ? sv : 0.0f;
  }
}

// ---------------- full A writer (zeros + diag + neighbors), replaces memset+scatter ----------------
__global__ void __launch_bounds__(256) k_writeA(const float* __restrict__ val,
                                                float* __restrict__ A) {
  int blk = blockIdx.x;                 // 16384 = bc*1024 + row
  int bc = blk >> 10, row = blk & 1023;
  int t = threadIdx.x;
  size_t base = (size_t)bc * HWN * HWN + (size_t)row * HWN;
  int pi = row >> 5, pj = row & 31;
  float4 o = make_float4(0.f, 0.f, 0.f, 0.f);
  if (((pi | pj) & 1) == 0) {
    int u = pi >> 1, v = pj >> 1;
    int s = u * 16 + v;
    __shared__ float sv[12];
    __shared__ float sInv;
    if (t < 12) sv[t] = val[(size_t)bc * PPAD + s * 12 + t];
    __syncthreads();
    if (t == 0) {
      float ssum = 1.f;
      for (int k = 0; k < 12; k++) ssum += sv[k];
      sInv = 1.f / (ssum + 1e-8f);
    }
    __syncthreads();
    float inv = sInv;
    float vo[4];
#pragma unroll
    for (int e = 0; e < 4; e++) {
      int col = t * 4 + e;
      float x = 0.f;
      if (col == row) {
        x = inv;
      } else if ((col & 33) == 0) {     // col even, grid-sampled column
        int cu = col >> 6, cv = (col & 31) >> 1;
        int du = cu - u + 2, dv = cv - v + 2;
        if (((unsigned)du < 5u) && ((unsigned)dv < 5u)) {
          int k = c_rk[du * 5 + dv];
          if (k >= 0) x = sv[k] * inv;
        }
      }
      vo[e] = x;
    }
    o = make_float4(vo[0], vo[1], vo[2], vo[3]);
  } else {
    if ((row >> 2) == t) {
      float dv = 1.0f / (1.0f + 1e-8f);
      int e = row & 3;
      if (e == 0) o.x = dv; else if (e == 1) o.y = dv;
      else if (e == 2) o.z = dv; else o.w = dv;
    }
  }
  reinterpret_cast<float4*>(A + base)[t] = o;
}

// ---------------- sparse diffusion + cam/conf outputs (row sums local) ----------------
__global__ void __launch_bounds__(256) k_diffuse(const float* __restrict__ cam,
    const float* __restrict__ val,
    const float* __restrict__ csc, const float* __restrict__ cbi,
    float* __restrict__ o_cam, float* __restrict__ o_conf) {
  int bc = blockIdx.x;
  int t = threadIdx.x;                 // = site s
  __shared__ float M[NS];
  int u = t >> 4, v = t & 15;
  int pix = (u << 6) + (v << 1);
  const float* camr = cam + (size_t)bc * HWN;
  float m = camr[pix];
  float vv[12];
  int nb[12];
  float ssum = 1.f;
#pragma unroll
  for (int k = 0; k < 12; k++) {
    int ub = u + c_du[k], vb = v + c_dv[k];
    bool vld = (ub >= 0) && (ub < 16) && (vb >= 0) && (vb < 16);
    nb[k] = vld ? ub * 16 + vb : t;
    vv[k] = vld ? val[(size_t)bc * PPAD + t * 12 + k] : 0.0f;
    ssum += vv[k];
  }
  float inv = 1.0f / (ssum + 1e-8f);
  float degn = ssum * inv;
  M[t] = m;
  __syncthreads();
  for (int step = 0; step < 3; step++) {
    float accv = m;
#pragma unroll
    for (int k = 0; k < 12; k++) accv = fmaf(vv[k], M[nb[k]], accv);
    float L = accv * inv - degn * m;
    m = fmaf(0.1f, L, m);
    __syncthreads();
    M[t] = m;
    __syncthreads();
  }
  float scale = csc[0], bias = cbi[0];
  for (int p = t; p < HWN; p += 256) {
    int ppi = p >> 5, ppj = p & 31;
    float x;
    if (((ppi | ppj) & 1) == 0) x = M[(ppi >> 1) * 16 + (ppj >> 1)];
    else x = camr[p];
    x = fminf(fmaxf(x, 0.0f), 1.0f);
    o_cam[(size_t)bc * HWN + p] = x;
    o_conf[(size_t)bc * HWN + p] = 1.0f / (1.0f + expf(-(scale * x + bias)));
  }
}

extern "C" void kernel_launch(void* const* d_in, const int* in_sizes, int n_in,
                              void* d_out, int out_size, void* d_ws, size_t ws_size,
                              hipStream_t stream) {
  const float* feat = (const float*)d_in[0];
  const float* cam  = (const float*)d_in[1];
  const float* eps  = (const float*)d_in[3];
  const float* cemb = (const float*)d_in[4];
  const float* aW1  = (const float*)d_in[5];
  const float* ab1  = (const float*)d_in[6];
  const float* aW2  = (const float*)d_in[7];
  const float* ab2  = (const float*)d_in[8];
  const float* aW3  = (const float*)d_in[9];
  const float* ab3  = (const float*)d_in[10];
  const float* muW1 = (const float*)d_in[11];
  const float* mub1 = (const float*)d_in[12];
  const float* muW2 = (const float*)d_in[13];
  const float* mub2 = (const float*)d_in[14];
  const float* lsW1 = (const float*)d_in[15];
  const float* lsb1 = (const float*)d_in[16];
  const float* lsW2 = (const float*)d_in[17];
  const float* lsb2 = (const float*)d_in[18];
  const float* csc  = (const float*)d_in[19];
  const float* cbi  = (const float*)d_in[20];

  float* out = (float*)d_out;
  float* o_cam  = out;                       // 16384
  float* o_zmu  = out + 16384;               // 64
  float* o_zls  = out + 16448;               // 64
  float* o_zs   = out + 16512;               // 64
  float* o_A    = out + 16576;               // 16777216
  float* o_conf = out + 16793792;            // 16384

  // scratch aliased into the (not-yet-written) A region; only val in d_ws
  float*  fg    = o_A;                                   // 6144 f32
  float*  EHb   = o_A + 6144;                            // 131072 f32
  ushort* g16   = (ushort*)(o_A + 137216);               // 2048*768 bf16
  ushort* WT16  = (ushort*)(o_A + 923648);               // 4*256*768 bf16
  ushort* W2T16 = (ushort*)(o_A + 1316864);              // 2*128*256 bf16
  ushort* Fb16  = (ushort*)(o_A + 1349632);              // 4*2048*256 bf16 (ends @2398208)
  float*  valb  = (float*)d_ws;                          // 16*3072 f32

  hipLaunchKernelGGL(k_pool, dim3(BB * DD), dim3(256), 0, stream, feat, fg, g16);
  hipLaunchKernelGGL(k_zmlp, dim3(BB), dim3(256), 0, stream, fg, muW1, mub1, muW2,
                     mub2, lsW1, lsb1, lsW2, lsb2, eps, o_zmu, o_zls, o_zs);
  hipLaunchKernelGGL(k_EH, dim3(512), dim3(256), 0, stream, cemb, aW1, ab1, EHb);
  hipLaunchKernelGGL(k_transpose, dim3(208), dim3(256), 0, stream, aW1, aW2, WT16, W2T16);
  hipLaunchKernelGGL(k_gemm_mfma, dim3(32, 4, 4), dim3(256), 0, stream, g16, WT16, EHb, Fb16);
  hipLaunchKernelGGL(k_pairmlp_mfma, dim3(768), dim3(256), 0, stream, Fb16, W2T16,
                     ab2, aW3, ab3, valb);
  hipLaunchKernelGGL(k_writeA, dim3(16384), dim3(256), 0, stream, valb, o_A);
  hipLaunchKernelGGL(k_diffuse, dim3(16), dim3(256), 0, stream, cam, valb,
                     csc, cbi, o_cam, o_conf);
}

// Round 5
// 98.691 us; speedup vs baseline: 1.8636x; 1.3015x over previous
//
#include <hip/hip_runtime.h>
#include <math.h>

#define BB 8
#define DD 768
#define HWN 1024
#define NS 256
#define PPAD 3072
#define O1 256
#define O2 128

typedef __attribute__((ext_vector_type(8))) short bf16x8;
typedef __attribute__((ext_vector_type(4))) float f32x4;

__constant__ int c_du[12] = {1,-1,0,0,2,-2,0,0,1, 1,-1,-1};
__constant__ int c_dv[12] = {0, 0,1,-1,0, 0,2,-2,1,-1, 1,-1};
// reverse map (du+2)*5+(dv+2) -> offset index k (-1 = not a neighbor)
__constant__ signed char c_rk[25] = {
  -1,-1, 5,-1,-1,
  -1,11, 1,10,-1,
   7, 3,-1, 2, 6,
  -1, 9, 0, 8,-1,
  -1,-1, 4,-1,-1};

__device__ inline ushort f2bf(float x) {
  unsigned u = __float_as_uint(x);
  u += 0x7FFF + ((u >> 16) & 1);
  return (ushort)(u >> 16);
}
__device__ inline float bf2f(ushort h) { return __uint_as_float(((unsigned)h) << 16); }

// ---------------- pooling + site gather (g bf16) ----------------
__global__ void __launch_bounds__(256) k_pool(const float* __restrict__ feat,
                                              float* __restrict__ fg,
                                              ushort* __restrict__ g16) {
  int row = blockIdx.x;                 // b*D + d
  int t = threadIdx.x;
  const float4 v = reinterpret_cast<const float4*>(feat + (size_t)row * HWN)[t];
  float s = v.x + v.y + v.z + v.w;
#pragma unroll
  for (int m = 32; m >= 1; m >>= 1) s += __shfl_xor(s, m, 64);
  __shared__ float red[4];
  if ((t & 63) == 0) red[t >> 6] = s;
  if ((t & 8) == 0) {
    int b = row / DD, d = row - b * DD;
    int u = t >> 4, r = t & 7;
    int s1 = u * 16 + 2 * r;
    g16[((size_t)(b * NS + s1)) * DD + d] = f2bf(v.x);
    g16[((size_t)(b * NS + s1 + 1)) * DD + d] = f2bf(v.z);
  }
  __syncthreads();
  if (t == 0) fg[row] = (red[0] + red[1] + red[2] + red[3]) * (1.0f / 1024.0f);
}

// ---------------- z layer-1 split-K partial GEMM ----------------
// grid (chunk=6, path=2, b=8); 256 thr = 4 row-groups x 64 col-threads (float4 cols)
__global__ void __launch_bounds__(256) k_zpart(const float* __restrict__ fg,
    const float* __restrict__ muW1, const float* __restrict__ lsW1,
    float* __restrict__ zscr) {
  int chunk = blockIdx.x, path = blockIdx.y, b = blockIdx.z;
  int t = threadIdx.x;
  int rg = t >> 6, ct = t & 63;
  __shared__ float sf[128];
  __shared__ __align__(16) float red[4][256];
  if (t < 128) sf[t] = fg[b * DD + chunk * 128 + t];
  __syncthreads();
  const float* W = (path ? lsW1 : muW1) + (size_t)(chunk * 128) * 256;
  float acc[4] = {0.f, 0.f, 0.f, 0.f};
#pragma unroll 4
  for (int it = 0; it < 32; it++) {
    int d = it * 4 + rg;
    float f = sf[d];
    float4 w = *reinterpret_cast<const float4*>(W + (size_t)d * 256 + ct * 4);
    acc[0] = fmaf(f, w.x, acc[0]);
    acc[1] = fmaf(f, w.y, acc[1]);
    acc[2] = fmaf(f, w.z, acc[2]);
    acc[3] = fmaf(f, w.w, acc[3]);
  }
  *reinterpret_cast<float4*>(&red[rg][ct * 4]) =
      make_float4(acc[0], acc[1], acc[2], acc[3]);
  __syncthreads();
  zscr[(((size_t)(b * 2 + path)) * 6 + chunk) * 256 + t] =
      red[0][t] + red[1][t] + red[2][t] + red[3][t];
}

// ---------------- z finish: sum chunks, relu, layer 2, sample ----------------
__global__ void __launch_bounds__(256) k_zfinish(const float* __restrict__ zscr,
    const float* __restrict__ mub1, const float* __restrict__ muW2,
    const float* __restrict__ mub2,
    const float* __restrict__ lsb1, const float* __restrict__ lsW2,
    const float* __restrict__ lsb2,
    const float* __restrict__ eps,
    float* __restrict__ o_zmu, float* __restrict__ o_zls, float* __restrict__ o_zs) {
  int b = blockIdx.x;
  int t = threadIdx.x;
  __shared__ float shm[256], shl[256];
  __shared__ float zres[2][8];
  float hm = mub1[t], hl = lsb1[t];
#pragma unroll
  for (int ch = 0; ch < 6; ch++) {
    hm += zscr[(((size_t)(b * 2 + 0)) * 6 + ch) * 256 + t];
    hl += zscr[(((size_t)(b * 2 + 1)) * 6 + ch) * 256 + t];
  }
  shm[t] = fmaxf(hm, 0.f);
  shl[t] = fmaxf(hl, 0.f);
  __syncthreads();
  if (t < 128 && (t & 63) < 8) {
    int path = t >> 6, kk = t & 7;
    const float* W2 = path ? lsW2 : muW2;
    const float* bi = path ? lsb2 : mub2;
    const float* sh = path ? shl : shm;
    float z = bi[kk];
    for (int i = 0; i < 256; i++) z = fmaf(sh[i], W2[i * 8 + kk], z);
    zres[path][kk] = z;
  }
  __syncthreads();
  if (t < 8) {
    float zm = zres[0][t], zl = zres[1][t];
    o_zmu[b * 8 + t] = zm;
    o_zls[b * 8 + t] = zl;
    o_zs[b * 8 + t] = zm + expf(zl) * eps[b * 8 + t];
  }
}

// ---------------- EH = 0.5*(coord_emb[site] @ W1_bot + b1), f32 ----------------
__global__ void __launch_bounds__(256) k_EH(const float* __restrict__ cemb,
                                            const float* __restrict__ W1,
                                            const float* __restrict__ b1,
                                            float* __restrict__ EH) {
  int bs = blockIdx.x;                  // c*256+s
  int c = bs >> 8, s = bs & 255;
  int u = s >> 4, v = s & 15;
  int pix = (u << 6) + (v << 1);
  __shared__ float ce[128];
  int t = threadIdx.x;
  if (t < 128) ce[t] = cemb[(size_t)pix * 128 + t];
  __syncthreads();
  const float* W = W1 + ((size_t)c * 1664 + 1536) * O1;
  float acc = 0.f;
  for (int e = 0; e < 128; e++) acc = fmaf(ce[e], W[(size_t)e * O1 + t], acc);
  EH[((size_t)(c * NS + s)) * O1 + t] = 0.5f * (acc + b1[c * O1 + t]);
}

// ---------------- transpose W1 (4 slices 768x256) + W2 (2x 256x128) to bf16 [n][k] ----------------
__global__ void __launch_bounds__(256) k_transpose(const float* __restrict__ W1,
    const float* __restrict__ W2, ushort* __restrict__ WT16, ushort* __restrict__ W2T16) {
  int blk = blockIdx.x, t = threadIdx.x;
  const float* src; ushort* dst; int K, N, k0, n0;
  if (blk < 192) {
    int ch = blk / 48, r = blk % 48;
    int c = ch & 1, half = ch >> 1;
    src = W1 + ((size_t)c * 1664 + half * 768) * 256;
    dst = WT16 + (size_t)ch * 256 * 768;
    K = 768; N = 256; k0 = (r >> 2) * 64; n0 = (r & 3) * 64;
  } else {
    int r = blk - 192;
    int c = r >> 3; int q = r & 7;
    src = W2 + (size_t)c * 256 * 128;
    dst = W2T16 + (size_t)c * 128 * 256;
    K = 256; N = 128; k0 = (q >> 1) * 64; n0 = (q & 1) * 64;
  }
  __shared__ float T[64][65];
  for (int i = 0; i < 16; i++) {
    int idx = i * 256 + t; int kl = idx >> 6, nl = idx & 63;
    T[kl][nl] = src[(size_t)(k0 + kl) * N + n0 + nl];
  }
  __syncthreads();
  for (int i = 0; i < 16; i++) {
    int idx = i * 256 + t; int nl = idx >> 6, kl = idx & 63;
    dst[(size_t)(n0 + nl) * K + k0 + kl] = f2bf(T[kl][nl]);
  }
}

// ---------------- MFMA site projection: Fb16[ch][2048][256] = g@W1slice + EH ----------------
__global__ void __launch_bounds__(256) k_gemm_mfma(const ushort* __restrict__ g16,
    const ushort* __restrict__ WT16, const float* __restrict__ EHb,
    ushort* __restrict__ Fb16) {
  int mt = blockIdx.x, nt = blockIdx.y, ch = blockIdx.z;
  int c = ch & 1;
  int row0 = mt * 64, col0 = nt * 64;
  int t = threadIdx.x;
  int wid = t >> 6, l = t & 63;
  int wm = wid & 1, wn = wid >> 1;
  int lm = l & 15, lk = (l >> 4) * 8;
  __shared__ float ehs[64][64];
  int s0 = row0 & 255;
  for (int i = 0; i < 16; i++) {
    int idx = i * 256 + t; int rl = idx >> 6, nl = idx & 63;
    ehs[rl][nl] = EHb[((size_t)(c * 256 + s0 + rl)) * 256 + col0 + nl];
  }
  f32x4 acc[2][2] = {};
  const ushort* ap0 = g16 + (size_t)(row0 + wm * 32 + lm) * DD + lk;
  const ushort* bp0 = WT16 + ((size_t)ch * 256 + col0 + wn * 32 + lm) * DD + lk;
#pragma unroll 4
  for (int k0 = 0; k0 < DD; k0 += 32) {
    bf16x8 a0 = *(const bf16x8*)(ap0 + k0);
    bf16x8 a1 = *(const bf16x8*)(ap0 + 16 * DD + k0);
    bf16x8 b0 = *(const bf16x8*)(bp0 + k0);
    bf16x8 b1 = *(const bf16x8*)(bp0 + 16 * DD + k0);
    acc[0][0] = __builtin_amdgcn_mfma_f32_16x16x32_bf16(a0, b0, acc[0][0], 0, 0, 0);
    acc[0][1] = __builtin_amdgcn_mfma_f32_16x16x32_bf16(a0, b1, acc[0][1], 0, 0, 0);
    acc[1][0] = __builtin_amdgcn_mfma_f32_16x16x32_bf16(a1, b0, acc[1][0], 0, 0, 0);
    acc[1][1] = __builtin_amdgcn_mfma_f32_16x16x32_bf16(a1, b1, acc[1][1], 0, 0, 0);
  }
  __syncthreads();
#pragma unroll
  for (int i = 0; i < 2; i++)
#pragma unroll
    for (int jj = 0; jj < 2; jj++)
#pragma unroll
      for (int r = 0; r < 4; r++) {
        int rm = wm * 32 + i * 16 + (l >> 4) * 4 + r;
        int cn = wn * 32 + jj * 16 + lm;
        float vo = acc[i][jj][r] + ehs[rm][cn];
        Fb16[((size_t)ch * 2048 + row0 + rm) * 256 + col0 + cn] = f2bf(vo);
      }
}

// ---------------- MFMA pair MLP: h1 = relu(F1[sa]+F2[sb]); layers 2+3 fused ----------------
__global__ void __launch_bounds__(256) k_pairmlp_mfma(const ushort* __restrict__ Fb16,
    const ushort* __restrict__ W2T16, const float* __restrict__ b2,
    const float* __restrict__ W3, const float* __restrict__ b3,
    float* __restrict__ val) {
  int blk = blockIdx.x;
  int bc = blk / 48, grp = blk - bc * 48;
  int b = bc >> 1, c = bc & 1;
  int t = threadIdx.x;
  int wid = t >> 6, l = t & 63;
  int wm = wid & 1, wn = wid >> 1;
  int lm = l & 15, lk = (l >> 4) * 8;
  __shared__ ushort h1s[64 * 256];     // 32 KB, XOR-swizzled
  __shared__ float psum[2][64];
  {
    int p_l = t >> 2, q = t & 3;
    int j = grp * 64 + p_l;
    int s = j / 12, ko = j - s * 12;
    int u = s >> 4, v = s & 15;
    int ub = u + c_du[ko], vb = v + c_dv[ko];
    bool vld = (ub >= 0) && (ub < 16) && (vb >= 0) && (vb < 16);
    int sb = vld ? ub * 16 + vb : s;
    const ushort* f1p = Fb16 + ((size_t)(c * 2048 + b * 256 + s)) * 256 + q * 64;
    const ushort* f2p = Fb16 + ((size_t)((2 + c) * 2048 + b * 256 + sb)) * 256 + q * 64;
    char* hb = (char*)h1s;
#pragma unroll
    for (int kk = 0; kk < 64; kk += 8) {
      bf16x8 x1 = *(const bf16x8*)(f1p + kk);
      bf16x8 x2 = *(const bf16x8*)(f2p + kk);
      bf16x8 o;
#pragma unroll
      for (int e = 0; e < 8; e++) {
        float a = bf2f((ushort)x1[e]) + bf2f((ushort)x2[e]);
        o[e] = (short)f2bf(fmaxf(a, 0.f));
      }
      int byt = (p_l * 512 + (q * 64 + kk) * 2) ^ ((p_l & 7) << 4);
      *(bf16x8*)(hb + byt) = o;
    }
  }
  __syncthreads();
  f32x4 acc[2][4] = {};
  const ushort* wp = W2T16 + ((size_t)(c * 128 + wn * 64 + lm)) * 256 + lk;
  const char* hb = (const char*)h1s;
  int p0 = wm * 32 + lm;
  int swz = (p0 & 7) << 4;
#pragma unroll 2
  for (int k0 = 0; k0 < 256; k0 += 32) {
    bf16x8 a0 = *(const bf16x8*)(hb + ((p0 * 512 + (k0 + lk) * 2) ^ swz));
    bf16x8 a1 = *(const bf16x8*)(hb + (((p0 + 16) * 512 + (k0 + lk) * 2) ^ swz));
#pragma unroll
    for (int nf = 0; nf < 4; nf++) {
      bf16x8 bb = *(const bf16x8*)(wp + nf * 16 * 256 + k0);
      acc[0][nf] = __builtin_amdgcn_mfma_f32_16x16x32_bf16(a0, bb, acc[0][nf], 0, 0, 0);
      acc[1][nf] = __builtin_amdgcn_mfma_f32_16x16x32_bf16(a1, bb, acc[1][nf], 0, 0, 0);
    }
  }
  float b2v[4], w3v[4];
#pragma unroll
  for (int nf = 0; nf < 4; nf++) {
    int col = wn * 64 + nf * 16 + lm;
    b2v[nf] = b2[c * 128 + col];
    w3v[nf] = W3[c * 128 + col];
  }
  float part[2][4];
#pragma unroll
  for (int mf = 0; mf < 2; mf++)
#pragma unroll
    for (int r = 0; r < 4; r++) {
      float ssum = 0.f;
#pragma unroll
      for (int nf = 0; nf < 4; nf++) {
        float h = fmaxf(acc[mf][nf][r] + b2v[nf], 0.f);
        ssum = fmaf(h, w3v[nf], ssum);
      }
      part[mf][r] = ssum;
    }
#pragma unroll
  for (int m = 1; m <= 8; m <<= 1)
#pragma unroll
    for (int mf = 0; mf < 2; mf++)
#pragma unroll
      for (int r = 0; r < 4; r++)
        part[mf][r] += __shfl_xor(part[mf][r], m, 64);
  if (lm == 0) {
#pragma unroll
    for (int mf = 0; mf < 2; mf++)
#pragma unroll
      for (int r = 0; r < 4; r++)
        psum[wn][wm * 32 + mf * 16 + (l >> 4) * 4 + r] = part[mf][r];
  }
  __syncthreads();
  if (t < 64) {
    int jj = grp * 64 + t;
    int ss = jj / 12, kk2 = jj - ss * 12;
    int uu = ss >> 4, vv2 = ss & 15;
    int ub2 = uu + c_du[kk2], vb2 = vv2 + c_dv[kk2];
    bool vld = (ub2 >= 0) && (ub2 < 16) && (vb2 >= 0) && (vb2 < 16);
    float lg = psum[0][t] + psum[1][t] + b3[c];
    float sv = 1.0f / (1.0f + expf(-lg));
    val[(size_t)bc * PPAD + jj] = vld ? sv : 0.0f;
  }
}

// ---------------- full A writer (zeros + diag + neighbors) ----------------
__global__ void __launch_bounds__(256) k_writeA(const float* __restrict__ val,
                                                float* __restrict__ A) {
  int blk = blockIdx.x;                 // 16384 = bc*1024 + row
  int bc = blk >> 10, row = blk & 1023;
  int t = threadIdx.x;
  size_t base = (size_t)bc * HWN * HWN + (size_t)row * HWN;
  int pi = row >> 5, pj = row & 31;
  float4 o = make_float4(0.f, 0.f, 0.f, 0.f);
  if (((pi | pj) & 1) == 0) {
    int u = pi >> 1, v = pj >> 1;
    int s = u * 16 + v;
    __shared__ float sv[12];
    __shared__ float sInv;
    if (t < 12) sv[t] = val[(size_t)bc * PPAD + s * 12 + t];
    __syncthreads();
    if (t == 0) {
      float ssum = 1.f;
      for (int k = 0; k < 12; k++) ssum += sv[k];
      sInv = 1.f / (ssum + 1e-8f);
    }
    __syncthreads();
    float inv = sInv;
    float vo[4];
#pragma unroll
    for (int e = 0; e < 4; e++) {
      int col = t * 4 + e;
      float x = 0.f;
      if (col == row) {
        x = inv;
      } else if ((col & 33) == 0) {     // col even, grid-sampled column
        int cu = col >> 6, cv = (col & 31) >> 1;
        int du = cu - u + 2, dv = cv - v + 2;
        if (((unsigned)du < 5u) && ((unsigned)dv < 5u)) {
          int k = c_rk[du * 5 + dv];
          if (k >= 0) x = sv[k] * inv;
        }
      }
      vo[e] = x;
    }
    o = make_float4(vo[0], vo[1], vo[2], vo[3]);
  } else {
    if ((row >> 2) == t) {
      float dv = 1.0f / (1.0f + 1e-8f);
      int e = row & 3;
      if (e == 0) o.x = dv; else if (e == 1) o.y = dv;
      else if (e == 2) o.z = dv; else o.w = dv;
    }
  }
  reinterpret_cast<float4*>(A + base)[t] = o;
}

// ---------------- sparse diffusion + cam/conf outputs ----------------
__global__ void __launch_bounds__(256) k_diffuse(const float* __restrict__ cam,
    const float* __restrict__ val,
    const float* __restrict__ csc, const float* __restrict__ cbi,
    float* __restrict__ o_cam, float* __restrict__ o_conf) {
  int bc = blockIdx.x;
  int t = threadIdx.x;                 // = site s
  __shared__ float M[NS];
  int u = t >> 4, v = t & 15;
  int pix = (u << 6) + (v << 1);
  const float* camr = cam + (size_t)bc * HWN;
  float m = camr[pix];
  float vv[12];
  int nb[12];
  float ssum = 1.f;
#pragma unroll
  for (int k = 0; k < 12; k++) {
    int ub = u + c_du[k], vb = v + c_dv[k];
    bool vld = (ub >= 0) && (ub < 16) && (vb >= 0) && (vb < 16);
    nb[k] = vld ? ub * 16 + vb : t;
    vv[k] = vld ? val[(size_t)bc * PPAD + t * 12 + k] : 0.0f;
    ssum += vv[k];
  }
  float inv = 1.0f / (ssum + 1e-8f);
  float degn = ssum * inv;
  M[t] = m;
  __syncthreads();
  for (int step = 0; step < 3; step++) {
    float accv = m;
#pragma unroll
    for (int k = 0; k < 12; k++) accv = fmaf(vv[k], M[nb[k]], accv);
    float L = accv * inv - degn * m;
    m = fmaf(0.1f, L, m);
    __syncthreads();
    M[t] = m;
    __syncthreads();
  }
  float scale = csc[0], bias = cbi[0];
  for (int p = t; p < HWN; p += 256) {
    int ppi = p >> 5, ppj = p & 31;
    float x;
    if (((ppi | ppj) & 1) == 0) x = M[(ppi >> 1) * 16 + (ppj >> 1)];
    else x = camr[p];
    x = fminf(fmaxf(x, 0.0f), 1.0f);
    o_cam[(size_t)bc * HWN + p] = x;
    o_conf[(size_t)bc * HWN + p] = 1.0f / (1.0f + expf(-(scale * x + bias)));
  }
}

extern "C" void kernel_launch(void* const* d_in, const int* in_sizes, int n_in,
                              void* d_out, int out_size, void* d_ws, size_t ws_size,
                              hipStream_t stream) {
  const float* feat = (const float*)d_in[0];
  const float* cam  = (const float*)d_in[1];
  const float* eps  = (const float*)d_in[3];
  const float* cemb = (const float*)d_in[4];
  const float* aW1  = (const float*)d_in[5];
  const float* ab1  = (const float*)d_in[6];
  const float* aW2  = (const float*)d_in[7];
  const float* ab2  = (const float*)d_in[8];
  const float* aW3  = (const float*)d_in[9];
  const float* ab3  = (const float*)d_in[10];
  const float* muW1 = (const float*)d_in[11];
  const float* mub1 = (const float*)d_in[12];
  const float* muW2 = (const float*)d_in[13];
  const float* mub2 = (const float*)d_in[14];
  const float* lsW1 = (const float*)d_in[15];
  const float* lsb1 = (const float*)d_in[16];
  const float* lsW2 = (const float*)d_in[17];
  const float* lsb2 = (const float*)d_in[18];
  const float* csc  = (const float*)d_in[19];
  const float* cbi  = (const float*)d_in[20];

  float* out = (float*)d_out;
  float* o_cam  = out;                       // 16384
  float* o_zmu  = out + 16384;               // 64
  float* o_zls  = out + 16448;               // 64
  float* o_zs   = out + 16512;               // 64
  float* o_A    = out + 16576;               // 16777216
  float* o_conf = out + 16793792;            // 16384

  // scratch aliased into the (not-yet-written) A region; only val in d_ws
  float*  fg    = o_A;                                   // 6144 f32
  float*  EHb   = o_A + 6144;                            // 131072 f32
  ushort* g16   = (ushort*)(o_A + 137216);               // 2048*768 bf16
  ushort* WT16  = (ushort*)(o_A + 923648);               // 4*256*768 bf16
  ushort* W2T16 = (ushort*)(o_A + 1316864);              // 2*128*256 bf16
  ushort* Fb16  = (ushort*)(o_A + 1349632);              // 4*2048*256 bf16 (ends @2398208)
  float*  zscr  = o_A + 2398208;                         // 8*2*6*256 f32 (ends @2422784)
  float*  valb  = (float*)d_ws;                          // 16*3072 f32

  hipLaunchKernelGGL(k_pool, dim3(BB * DD), dim3(256), 0, stream, feat, fg, g16);
  hipLaunchKernelGGL(k_zpart, dim3(6, 2, BB), dim3(256), 0, stream, fg, muW1, lsW1, zscr);
  hipLaunchKernelGGL(k_zfinish, dim3(BB), dim3(256), 0, stream, zscr, mub1, muW2,
                     mub2, lsb1, lsW2, lsb2, eps, o_zmu, o_zls, o_zs);
  hipLaunchKernelGGL(k_EH, dim3(512), dim3(256), 0, stream, cemb, aW1, ab1, EHb);
  hipLaunchKernelGGL(k_transpose, dim3(208), dim3(256), 0, stream, aW1, aW2, WT16, W2T16);
  hipLaunchKernelGGL(k_gemm_mfma, dim3(32, 4, 4), dim3(256), 0, stream, g16, WT16, EHb, Fb16);
  hipLaunchKernelGGL(k_pairmlp_mfma, dim3(768), dim3(256), 0, stream, Fb16, W2T16,
                     ab2, aW3, ab3, valb);
  hipLaunchKernelGGL(k_writeA, dim3(16384), dim3(256), 0, stream, valb, o_A);
  hipLaunchKernelGGL(k_diffuse, dim3(16), dim3(256), 0, stream, cam, valb,
                     csc, cbi, o_cam, o_conf);
}

// Round 6
// 85.080 us; speedup vs baseline: 2.1617x; 1.1600x over previous
//
#include <hip/hip_runtime.h>
#include <math.h>

#define BB 8
#define DD 768
#define HWN 1024
#define NS 256
#define PPAD 3072
#define O1 256
#define O2 128

typedef __attribute__((ext_vector_type(8))) short bf16x8;
typedef __attribute__((ext_vector_type(4))) float f32x4;

__constant__ int c_du[12] = {1,-1,0,0,2,-2,0,0,1, 1,-1,-1};
__constant__ int c_dv[12] = {0, 0,1,-1,0, 0,2,-2,1,-1, 1,-1};
__constant__ signed char c_rk[25] = {
  -1,-1, 5,-1,-1,
  -1,11, 1,10,-1,
   7, 3,-1, 2, 6,
  -1, 9, 0, 8,-1,
  -1,-1, 4,-1,-1};

__device__ inline ushort f2bf(float x) {
  unsigned u = __float_as_uint(x);
  u += 0x7FFF + ((u >> 16) & 1);
  return (ushort)(u >> 16);
}
__device__ inline float bf2f(ushort h) { return __uint_as_float(((unsigned)h) << 16); }

// ============ k_pre: pool(6144) | EH(512) | transpose(208) ============
__global__ void __launch_bounds__(256) k_pre(const float* __restrict__ feat,
    const float* __restrict__ cemb, const float* __restrict__ W1,
    const float* __restrict__ b1, const float* __restrict__ W2,
    float* __restrict__ fg, ushort* __restrict__ g16,
    float* __restrict__ EH, ushort* __restrict__ WT16, ushort* __restrict__ W2T16) {
  __shared__ __align__(16) float sm[64 * 65];
  int blk = blockIdx.x;
  int t = threadIdx.x;
  if (blk < 6144) {
    // ---- pool ----
    int row = blk;
    const float4 v = reinterpret_cast<const float4*>(feat + (size_t)row * HWN)[t];
    float s = v.x + v.y + v.z + v.w;
#pragma unroll
    for (int m = 32; m >= 1; m >>= 1) s += __shfl_xor(s, m, 64);
    if ((t & 63) == 0) sm[t >> 6] = s;
    if ((t & 8) == 0) {
      int b = row / DD, d = row - b * DD;
      int u = t >> 4, r = t & 7;
      int s1 = u * 16 + 2 * r;
      g16[((size_t)(b * NS + s1)) * DD + d] = f2bf(v.x);
      g16[((size_t)(b * NS + s1 + 1)) * DD + d] = f2bf(v.z);
    }
    __syncthreads();
    if (t == 0) fg[row] = (sm[0] + sm[1] + sm[2] + sm[3]) * (1.0f / 1024.0f);
  } else if (blk < 6656) {
    // ---- EH ----
    int bs = blk - 6144;
    int c = bs >> 8, s = bs & 255;
    int u = s >> 4, v = s & 15;
    int pix = (u << 6) + (v << 1);
    float* ce = sm;
    if (t < 128) ce[t] = cemb[(size_t)pix * 128 + t];
    __syncthreads();
    const float* W = W1 + ((size_t)c * 1664 + 1536) * O1;
    float acc = 0.f;
    for (int e = 0; e < 128; e++) acc = fmaf(ce[e], W[(size_t)e * O1 + t], acc);
    EH[((size_t)(c * NS + s)) * O1 + t] = 0.5f * (acc + b1[c * O1 + t]);
  } else {
    // ---- transpose ----
    int r0 = blk - 6656;
    const float* src; ushort* dst; int K, N, k0, n0;
    if (r0 < 192) {
      int ch = r0 / 48, r = r0 % 48;
      int c = ch & 1, half = ch >> 1;
      src = W1 + ((size_t)c * 1664 + half * 768) * 256;
      dst = WT16 + (size_t)ch * 256 * 768;
      K = 768; N = 256; k0 = (r >> 2) * 64; n0 = (r & 3) * 64;
    } else {
      int r = r0 - 192;
      int c = r >> 3; int q = r & 7;
      src = W2 + (size_t)c * 256 * 128;
      dst = W2T16 + (size_t)c * 128 * 256;
      K = 256; N = 128; k0 = (q >> 1) * 64; n0 = (q & 1) * 64;
    }
    float (*T)[65] = reinterpret_cast<float(*)[65]>(sm);
    for (int i = 0; i < 16; i++) {
      int idx = i * 256 + t; int kl = idx >> 6, nl = idx & 63;
      T[kl][nl] = src[(size_t)(k0 + kl) * N + n0 + nl];
    }
    __syncthreads();
    for (int i = 0; i < 16; i++) {
      int idx = i * 256 + t; int nl = idx >> 6, kl = idx & 63;
      dst[(size_t)(n0 + nl) * K + k0 + kl] = f2bf(T[kl][nl]);
    }
  }
}

// ============ k_mid: gemm_mfma(512) | zpart(96) ============
__global__ void __launch_bounds__(256) k_mid(const ushort* __restrict__ g16,
    const ushort* __restrict__ WT16, const float* __restrict__ EHb,
    const float* __restrict__ fg, const float* __restrict__ muW1,
    const float* __restrict__ lsW1,
    ushort* __restrict__ Fb16, float* __restrict__ zscr) {
  __shared__ __align__(16) float sm[4096];
  int blk = blockIdx.x;
  int t = threadIdx.x;
  if (blk < 512) {
    // ---- gemm_mfma ----
    int mt = blk & 31, nt = (blk >> 5) & 3, ch = blk >> 7;
    int c = ch & 1;
    int row0 = mt * 64, col0 = nt * 64;
    int wid = t >> 6, l = t & 63;
    int wm = wid & 1, wn = wid >> 1;
    int lm = l & 15, lk = (l >> 4) * 8;
    float (*ehs)[64] = reinterpret_cast<float(*)[64]>(sm);
    int s0 = row0 & 255;
    for (int i = 0; i < 16; i++) {
      int idx = i * 256 + t; int rl = idx >> 6, nl = idx & 63;
      ehs[rl][nl] = EHb[((size_t)(c * 256 + s0 + rl)) * 256 + col0 + nl];
    }
    f32x4 acc[2][2] = {};
    const ushort* ap0 = g16 + (size_t)(row0 + wm * 32 + lm) * DD + lk;
    const ushort* bp0 = WT16 + ((size_t)ch * 256 + col0 + wn * 32 + lm) * DD + lk;
#pragma unroll 4
    for (int k0 = 0; k0 < DD; k0 += 32) {
      bf16x8 a0 = *(const bf16x8*)(ap0 + k0);
      bf16x8 a1 = *(const bf16x8*)(ap0 + 16 * DD + k0);
      bf16x8 b0 = *(const bf16x8*)(bp0 + k0);
      bf16x8 b1 = *(const bf16x8*)(bp0 + 16 * DD + k0);
      acc[0][0] = __builtin_amdgcn_mfma_f32_16x16x32_bf16(a0, b0, acc[0][0], 0, 0, 0);
      acc[0][1] = __builtin_amdgcn_mfma_f32_16x16x32_bf16(a0, b1, acc[0][1], 0, 0, 0);
      acc[1][0] = __builtin_amdgcn_mfma_f32_16x16x32_bf16(a1, b0, acc[1][0], 0, 0, 0);
      acc[1][1] = __builtin_amdgcn_mfma_f32_16x16x32_bf16(a1, b1, acc[1][1], 0, 0, 0);
    }
    __syncthreads();
#pragma unroll
    for (int i = 0; i < 2; i++)
#pragma unroll
      for (int jj = 0; jj < 2; jj++)
#pragma unroll
        for (int r = 0; r < 4; r++) {
          int rm = wm * 32 + i * 16 + (l >> 4) * 4 + r;
          int cn = wn * 32 + jj * 16 + lm;
          float vo = acc[i][jj][r] + ehs[rm][cn];
          Fb16[((size_t)ch * 2048 + row0 + rm) * 256 + col0 + cn] = f2bf(vo);
        }
  } else {
    // ---- zpart ----
    int i = blk - 512;
    int chunk = i % 6, path = (i / 6) & 1, b = i / 12;
    int rg = t >> 6, ct = t & 63;
    float* sf = sm;
    float (*red)[256] = reinterpret_cast<float(*)[256]>(sm + 128);
    if (t < 128) sf[t] = fg[b * DD + chunk * 128 + t];
    __syncthreads();
    const float* W = (path ? lsW1 : muW1) + (size_t)(chunk * 128) * 256;
    float acc[4] = {0.f, 0.f, 0.f, 0.f};
#pragma unroll 4
    for (int it = 0; it < 32; it++) {
      int d = it * 4 + rg;
      float f = sf[d];
      float4 w = *reinterpret_cast<const float4*>(W + (size_t)d * 256 + ct * 4);
      acc[0] = fmaf(f, w.x, acc[0]);
      acc[1] = fmaf(f, w.y, acc[1]);
      acc[2] = fmaf(f, w.z, acc[2]);
      acc[3] = fmaf(f, w.w, acc[3]);
    }
    *reinterpret_cast<float4*>(&red[rg][ct * 4]) =
        make_float4(acc[0], acc[1], acc[2], acc[3]);
    __syncthreads();
    zscr[(((size_t)(b * 2 + path)) * 6 + chunk) * 256 + t] =
        red[0][t] + red[1][t] + red[2][t] + red[3][t];
  }
}

// ============ k_pair: pairmlp(768) | zfinish(8) ============
__global__ void __launch_bounds__(256) k_pair(const ushort* __restrict__ Fb16,
    const ushort* __restrict__ W2T16, const float* __restrict__ b2,
    const float* __restrict__ W3, const float* __restrict__ b3,
    const float* __restrict__ zscr,
    const float* __restrict__ mub1, const float* __restrict__ muW2,
    const float* __restrict__ mub2,
    const float* __restrict__ lsb1, const float* __restrict__ lsW2,
    const float* __restrict__ lsb2, const float* __restrict__ eps,
    float* __restrict__ val,
    float* __restrict__ o_zmu, float* __restrict__ o_zls, float* __restrict__ o_zs) {
  __shared__ __align__(16) ushort h1s[64 * 256];
  __shared__ float psum2[2][64];
  int blk = blockIdx.x;
  int t = threadIdx.x;
  if (blk < 768) {
    // ---- pairmlp ----
    int bc = blk / 48, grp = blk - bc * 48;
    int b = bc >> 1, c = bc & 1;
    int wid = t >> 6, l = t & 63;
    int wm = wid & 1, wn = wid >> 1;
    int lm = l & 15, lk = (l >> 4) * 8;
    {
      int p_l = t >> 2, q = t & 3;
      int j = grp * 64 + p_l;
      int s = j / 12, ko = j - s * 12;
      int u = s >> 4, v = s & 15;
      int ub = u + c_du[ko], vb = v + c_dv[ko];
      bool vld = (ub >= 0) && (ub < 16) && (vb >= 0) && (vb < 16);
      int sb = vld ? ub * 16 + vb : s;
      const ushort* f1p = Fb16 + ((size_t)(c * 2048 + b * 256 + s)) * 256 + q * 64;
      const ushort* f2p = Fb16 + ((size_t)((2 + c) * 2048 + b * 256 + sb)) * 256 + q * 64;
      char* hb = (char*)h1s;
#pragma unroll
      for (int kk = 0; kk < 64; kk += 8) {
        bf16x8 x1 = *(const bf16x8*)(f1p + kk);
        bf16x8 x2 = *(const bf16x8*)(f2p + kk);
        bf16x8 o;
#pragma unroll
        for (int e = 0; e < 8; e++) {
          float a = bf2f((ushort)x1[e]) + bf2f((ushort)x2[e]);
          o[e] = (short)f2bf(fmaxf(a, 0.f));
        }
        int byt = (p_l * 512 + (q * 64 + kk) * 2) ^ ((p_l & 7) << 4);
        *(bf16x8*)(hb + byt) = o;
      }
    }
    __syncthreads();
    f32x4 acc[2][4] = {};
    const ushort* wp = W2T16 + ((size_t)(c * 128 + wn * 64 + lm)) * 256 + lk;
    const char* hb = (const char*)h1s;
    int p0 = wm * 32 + lm;
    int swz = (p0 & 7) << 4;
#pragma unroll 2
    for (int k0 = 0; k0 < 256; k0 += 32) {
      bf16x8 a0 = *(const bf16x8*)(hb + ((p0 * 512 + (k0 + lk) * 2) ^ swz));
      bf16x8 a1 = *(const bf16x8*)(hb + (((p0 + 16) * 512 + (k0 + lk) * 2) ^ swz));
#pragma unroll
      for (int nf = 0; nf < 4; nf++) {
        bf16x8 bb = *(const bf16x8*)(wp + nf * 16 * 256 + k0);
        acc[0][nf] = __builtin_amdgcn_mfma_f32_16x16x32_bf16(a0, bb, acc[0][nf], 0, 0, 0);
        acc[1][nf] = __builtin_amdgcn_mfma_f32_16x16x32_bf16(a1, bb, acc[1][nf], 0, 0, 0);
      }
    }
    float b2v[4], w3v[4];
#pragma unroll
    for (int nf = 0; nf < 4; nf++) {
      int col = wn * 64 + nf * 16 + lm;
      b2v[nf] = b2[c * 128 + col];
      w3v[nf] = W3[c * 128 + col];
    }
    float part[2][4];
#pragma unroll
    for (int mf = 0; mf < 2; mf++)
#pragma unroll
      for (int r = 0; r < 4; r++) {
        float ssum = 0.f;
#pragma unroll
        for (int nf = 0; nf < 4; nf++) {
          float h = fmaxf(acc[mf][nf][r] + b2v[nf], 0.f);
          ssum = fmaf(h, w3v[nf], ssum);
        }
        part[mf][r] = ssum;
      }
#pragma unroll
    for (int m = 1; m <= 8; m <<= 1)
#pragma unroll
      for (int mf = 0; mf < 2; mf++)
#pragma unroll
        for (int r = 0; r < 4; r++)
          part[mf][r] += __shfl_xor(part[mf][r], m, 64);
    if (lm == 0) {
#pragma unroll
      for (int mf = 0; mf < 2; mf++)
#pragma unroll
        for (int r = 0; r < 4; r++)
          psum2[wn][wm * 32 + mf * 16 + (l >> 4) * 4 + r] = part[mf][r];
    }
    __syncthreads();
    if (t < 64) {
      int jj = grp * 64 + t;
      int ss = jj / 12, kk2 = jj - ss * 12;
      int uu = ss >> 4, vv2 = ss & 15;
      int ub2 = uu + c_du[kk2], vb2 = vv2 + c_dv[kk2];
      bool vld = (ub2 >= 0) && (ub2 < 16) && (vb2 >= 0) && (vb2 < 16);
      float lg = psum2[0][t] + psum2[1][t] + b3[c];
      float sv = 1.0f / (1.0f + expf(-lg));
      val[(size_t)bc * PPAD + jj] = vld ? sv : 0.0f;
    }
  } else {
    // ---- zfinish ----
    int b = blk - 768;
    float* shm = (float*)h1s;
    float* shl = shm + 256;
    float* zres = shm + 512;          // 2*8
    float hm = mub1[t], hl = lsb1[t];
#pragma unroll
    for (int ch = 0; ch < 6; ch++) {
      hm += zscr[(((size_t)(b * 2 + 0)) * 6 + ch) * 256 + t];
      hl += zscr[(((size_t)(b * 2 + 1)) * 6 + ch) * 256 + t];
    }
    shm[t] = fmaxf(hm, 0.f);
    shl[t] = fmaxf(hl, 0.f);
    __syncthreads();
    if (t < 128 && (t & 63) < 8) {
      int path = t >> 6, kk = t & 7;
      const float* W2p = path ? lsW2 : muW2;
      const float* bi = path ? lsb2 : mub2;
      const float* sh = path ? shl : shm;
      float z = bi[kk];
      for (int i = 0; i < 256; i++) z = fmaf(sh[i], W2p[i * 8 + kk], z);
      zres[path * 8 + kk] = z;
    }
    __syncthreads();
    if (t < 8) {
      float zm = zres[t], zl = zres[8 + t];
      o_zmu[b * 8 + t] = zm;
      o_zls[b * 8 + t] = zl;
      o_zs[b * 8 + t] = zm + expf(zl) * eps[b * 8 + t];
    }
  }
}

// ============ k_final: writeA(16384) | diffuse(16) ============
__global__ void __launch_bounds__(256) k_final(const float* __restrict__ val,
    const float* __restrict__ cam,
    const float* __restrict__ csc, const float* __restrict__ cbi,
    float* __restrict__ A, float* __restrict__ o_cam, float* __restrict__ o_conf) {
  __shared__ float smf[260];
  int blk = blockIdx.x;
  int t = threadIdx.x;
  if (blk < 16384) {
    // ---- writeA ----
    int bc = blk >> 10, row = blk & 1023;
    size_t base = (size_t)bc * HWN * HWN + (size_t)row * HWN;
    int pi = row >> 5, pj = row & 31;
    float4 o = make_float4(0.f, 0.f, 0.f, 0.f);
    if (((pi | pj) & 1) == 0) {
      int u = pi >> 1, v = pj >> 1;
      int s = u * 16 + v;
      float* sv = smf;
      if (t < 12) sv[t] = val[(size_t)bc * PPAD + s * 12 + t];
      __syncthreads();
      if (t == 0) {
        float ssum = 1.f;
        for (int k = 0; k < 12; k++) ssum += sv[k];
        smf[12] = 1.f / (ssum + 1e-8f);
      }
      __syncthreads();
      float inv = smf[12];
      float vo[4];
#pragma unroll
      for (int e = 0; e < 4; e++) {
        int col = t * 4 + e;
        float x = 0.f;
        if (col == row) {
          x = inv;
        } else if ((col & 33) == 0) {
          int cu = col >> 6, cv = (col & 31) >> 1;
          int du = cu - u + 2, dv = cv - v + 2;
          if (((unsigned)du < 5u) && ((unsigned)dv < 5u)) {
            int k = c_rk[du * 5 + dv];
            if (k >= 0) x = sv[k] * inv;
          }
        }
        vo[e] = x;
      }
      o = make_float4(vo[0], vo[1], vo[2], vo[3]);
    } else {
      if ((row >> 2) == t) {
        float dv = 1.0f / (1.0f + 1e-8f);
        int e = row & 3;
        if (e == 0) o.x = dv; else if (e == 1) o.y = dv;
        else if (e == 2) o.z = dv; else o.w = dv;
      }
    }
    reinterpret_cast<float4*>(A + base)[t] = o;
  } else {
    // ---- diffuse ----
    int bc = blk - 16384;
    float* M = smf;
    int u = t >> 4, v = t & 15;
    int pix = (u << 6) + (v << 1);
    const float* camr = cam + (size_t)bc * HWN;
    float m = camr[pix];
    float vv[12];
    int nb[12];
    float ssum = 1.f;
#pragma unroll
    for (int k = 0; k < 12; k++) {
      int ub = u + c_du[k], vb = v + c_dv[k];
      bool vld = (ub >= 0) && (ub < 16) && (vb >= 0) && (vb < 16);
      nb[k] = vld ? ub * 16 + vb : t;
      vv[k] = vld ? val[(size_t)bc * PPAD + t * 12 + k] : 0.0f;
      ssum += vv[k];
    }
    float inv = 1.0f / (ssum + 1e-8f);
    float degn = ssum * inv;
    M[t] = m;
    __syncthreads();
    for (int step = 0; step < 3; step++) {
      float accv = m;
#pragma unroll
      for (int k = 0; k < 12; k++) accv = fmaf(vv[k], M[nb[k]], accv);
      float L = accv * inv - degn * m;
      m = fmaf(0.1f, L, m);
      __syncthreads();
      M[t] = m;
      __syncthreads();
    }
    float scale = csc[0], bias = cbi[0];
    for (int p = t; p < HWN; p += 256) {
      int ppi = p >> 5, ppj = p & 31;
      float x;
      if (((ppi | ppj) & 1) == 0) x = M[(ppi >> 1) * 16 + (ppj >> 1)];
      else x = camr[p];
      x = fminf(fmaxf(x, 0.0f), 1.0f);
      o_cam[(size_t)bc * HWN + p] = x;
      o_conf[(size_t)bc * HWN + p] = 1.0f / (1.0f + expf(-(scale * x + bias)));
    }
  }
}

extern "C" void kernel_launch(void* const* d_in, const int* in_sizes, int n_in,
                              void* d_out, int out_size, void* d_ws, size_t ws_size,
                              hipStream_t stream) {
  const float* feat = (const float*)d_in[0];
  const float* cam  = (const float*)d_in[1];
  const float* eps  = (const float*)d_in[3];
  const float* cemb = (const float*)d_in[4];
  const float* aW1  = (const float*)d_in[5];
  const float* ab1  = (const float*)d_in[6];
  const float* aW2  = (const float*)d_in[7];
  const float* ab2  = (const float*)d_in[8];
  const float* aW3  = (const float*)d_in[9];
  const float* ab3  = (const float*)d_in[10];
  const float* muW1 = (const float*)d_in[11];
  const float* mub1 = (const float*)d_in[12];
  const float* muW2 = (const float*)d_in[13];
  const float* mub2 = (const float*)d_in[14];
  const float* lsW1 = (const float*)d_in[15];
  const float* lsb1 = (const float*)d_in[16];
  const float* lsW2 = (const float*)d_in[17];
  const float* lsb2 = (const float*)d_in[18];
  const float* csc  = (const float*)d_in[19];
  const float* cbi  = (const float*)d_in[20];

  float* out = (float*)d_out;
  float* o_cam  = out;                       // 16384
  float* o_zmu  = out + 16384;               // 64
  float* o_zls  = out + 16448;               // 64
  float* o_zs   = out + 16512;               // 64
  float* o_A    = out + 16576;               // 16777216
  float* o_conf = out + 16793792;            // 16384

  // scratch aliased into the (not-yet-written) A region; only val in d_ws
  float*  fg    = o_A;                                   // 6144 f32
  float*  EHb   = o_A + 6144;                            // 131072 f32
  ushort* g16   = (ushort*)(o_A + 137216);               // 2048*768 bf16
  ushort* WT16  = (ushort*)(o_A + 923648);               // 4*256*768 bf16
  ushort* W2T16 = (ushort*)(o_A + 1316864);              // 2*128*256 bf16
  ushort* Fb16  = (ushort*)(o_A + 1349632);              // 4*2048*256 bf16 (ends @2398208)
  float*  zscr  = o_A + 2398208;                         // 8*2*6*256 f32 (ends @2422784)
  float*  valb  = (float*)d_ws;                          // 16*3072 f32

  hipLaunchKernelGGL(k_pre, dim3(6864), dim3(256), 0, stream,
                     feat, cemb, aW1, ab1, aW2, fg, g16, EHb, WT16, W2T16);
  hipLaunchKernelGGL(k_mid, dim3(608), dim3(256), 0, stream,
                     g16, WT16, EHb, fg, muW1, lsW1, Fb16, zscr);
  hipLaunchKernelGGL(k_pair, dim3(776), dim3(256), 0, stream,
                     Fb16, W2T16, ab2, aW3, ab3, zscr,
                     mub1, muW2, mub2, lsb1, lsW2, lsb2, eps,
                     valb, o_zmu, o_zls, o_zs);
  hipLaunchKernelGGL(k_final, dim3(16400), dim3(256), 0, stream,
                     valb, cam, csc, cbi, o_A, o_cam, o_conf);
}

// Round 7
// 83.699 us; speedup vs baseline: 2.1973x; 1.0165x over previous
//
#include <hip/hip_runtime.h>
#include <math.h>

#define BB 8
#define DD 768
#define HWN 1024
#define NS 256
#define PPAD 3072
#define O1 256
#define O2 128
// scratch aliased into A ends exactly at global row 2366 (float 2422784)
#define SCRATCH_ROWS 2366
#define FILL_SPLIT 7009   // (16384-2366)/2 rows filled by k_mid, rest by k_pair

typedef __attribute__((ext_vector_type(8))) short bf16x8;
typedef __attribute__((ext_vector_type(4))) float f32x4;

__constant__ int c_du[12] = {1,-1,0,0,2,-2,0,0,1, 1,-1,-1};
__constant__ int c_dv[12] = {0, 0,1,-1,0, 0,2,-2,1,-1, 1,-1};
__constant__ signed char c_rk[25] = {
  -1,-1, 5,-1,-1,
  -1,11, 1,10,-1,
   7, 3,-1, 2, 6,
  -1, 9, 0, 8,-1,
  -1,-1, 4,-1,-1};

__device__ inline ushort f2bf(float x) {
  unsigned u = __float_as_uint(x);
  u += 0x7FFF + ((u >> 16) & 1);
  return (ushort)(u >> 16);
}
__device__ inline float bf2f(ushort h) { return __uint_as_float(((unsigned)h) << 16); }

// write one identity row of A (zeros + diag); row given by global row index r_g
__device__ inline void identity_row(float* __restrict__ A, int r_g, int t) {
  int row = r_g & 1023;
  float4 o = make_float4(0.f, 0.f, 0.f, 0.f);
  if ((row >> 2) == t) {
    float dv = 1.0f / (1.0f + 1e-8f);
    int e = row & 3;
    if (e == 0) o.x = dv; else if (e == 1) o.y = dv;
    else if (e == 2) o.z = dv; else o.w = dv;
  }
  reinterpret_cast<float4*>(A + (size_t)r_g * 1024)[t] = o;
}
__device__ inline bool row_sampled(int row) {
  return ((row | (row >> 5)) & 1) == 0;   // pi=row>>5, pj=row&31 both even
}

// ============ k_pre: pool(6144) | EH(512) | transpose(208) ============
__global__ void __launch_bounds__(256) k_pre(const float* __restrict__ feat,
    const float* __restrict__ cemb, const float* __restrict__ W1,
    const float* __restrict__ b1, const float* __restrict__ W2,
    float* __restrict__ fg, ushort* __restrict__ g16,
    float* __restrict__ EH, ushort* __restrict__ WT16, ushort* __restrict__ W2T16) {
  __shared__ __align__(16) float sm[64 * 65];
  int blk = blockIdx.x;
  int t = threadIdx.x;
  if (blk < 6144) {
    // ---- pool ----
    int row = blk;
    const float4 v = reinterpret_cast<const float4*>(feat + (size_t)row * HWN)[t];
    float s = v.x + v.y + v.z + v.w;
#pragma unroll
    for (int m = 32; m >= 1; m >>= 1) s += __shfl_xor(s, m, 64);
    if ((t & 63) == 0) sm[t >> 6] = s;
    if ((t & 8) == 0) {
      int b = row / DD, d = row - b * DD;
      int u = t >> 4, r = t & 7;
      int s1 = u * 16 + 2 * r;
      g16[((size_t)(b * NS + s1)) * DD + d] = f2bf(v.x);
      g16[((size_t)(b * NS + s1 + 1)) * DD + d] = f2bf(v.z);
    }
    __syncthreads();
    if (t == 0) fg[row] = (sm[0] + sm[1] + sm[2] + sm[3]) * (1.0f / 1024.0f);
  } else if (blk < 6656) {
    // ---- EH ----
    int bs = blk - 6144;
    int c = bs >> 8, s = bs & 255;
    int u = s >> 4, v = s & 15;
    int pix = (u << 6) + (v << 1);
    float* ce = sm;
    if (t < 128) ce[t] = cemb[(size_t)pix * 128 + t];
    __syncthreads();
    const float* W = W1 + ((size_t)c * 1664 + 1536) * O1;
    float acc = 0.f;
    for (int e = 0; e < 128; e++) acc = fmaf(ce[e], W[(size_t)e * O1 + t], acc);
    EH[((size_t)(c * NS + s)) * O1 + t] = 0.5f * (acc + b1[c * O1 + t]);
  } else {
    // ---- transpose ----
    int r0 = blk - 6656;
    const float* src; ushort* dst; int K, N, k0, n0;
    if (r0 < 192) {
      int ch = r0 / 48, r = r0 % 48;
      int c = ch & 1, half = ch >> 1;
      src = W1 + ((size_t)c * 1664 + half * 768) * 256;
      dst = WT16 + (size_t)ch * 256 * 768;
      K = 768; N = 256; k0 = (r >> 2) * 64; n0 = (r & 3) * 64;
    } else {
      int r = r0 - 192;
      int c = r >> 3; int q = r & 7;
      src = W2 + (size_t)c * 256 * 128;
      dst = W2T16 + (size_t)c * 128 * 256;
      K = 256; N = 128; k0 = (q >> 1) * 64; n0 = (q & 1) * 64;
    }
    float (*T)[65] = reinterpret_cast<float(*)[65]>(sm);
    for (int i = 0; i < 16; i++) {
      int idx = i * 256 + t; int kl = idx >> 6, nl = idx & 63;
      T[kl][nl] = src[(size_t)(k0 + kl) * N + n0 + nl];
    }
    __syncthreads();
    for (int i = 0; i < 16; i++) {
      int idx = i * 256 + t; int nl = idx >> 6, kl = idx & 63;
      dst[(size_t)(n0 + nl) * K + k0 + kl] = f2bf(T[kl][nl]);
    }
  }
}

// ============ k_mid: gemm_mfma(512) | zpart(96) | A-identity fill ============
__global__ void __launch_bounds__(256) k_mid(const ushort* __restrict__ g16,
    const ushort* __restrict__ WT16, const float* __restrict__ EHb,
    const float* __restrict__ fg, const float* __restrict__ muW1,
    const float* __restrict__ lsW1,
    ushort* __restrict__ Fb16, float* __restrict__ zscr, float* __restrict__ A) {
  __shared__ __align__(16) float sm[4096];
  int blk = blockIdx.x;
  int t = threadIdx.x;
  if (blk >= 608) {
    // ---- identity fill, rows [SCRATCH_ROWS, SCRATCH_ROWS+FILL_SPLIT) ----
    int r_g = SCRATCH_ROWS + (blk - 608);
    if (!row_sampled(r_g & 1023)) identity_row(A, r_g, t);
    return;
  }
  if (blk < 512) {
    // ---- gemm_mfma ----
    int mt = blk & 31, nt = (blk >> 5) & 3, ch = blk >> 7;
    int c = ch & 1;
    int row0 = mt * 64, col0 = nt * 64;
    int wid = t >> 6, l = t & 63;
    int wm = wid & 1, wn = wid >> 1;
    int lm = l & 15, lk = (l >> 4) * 8;
    float (*ehs)[64] = reinterpret_cast<float(*)[64]>(sm);
    int s0 = row0 & 255;
    for (int i = 0; i < 16; i++) {
      int idx = i * 256 + t; int rl = idx >> 6, nl = idx & 63;
      ehs[rl][nl] = EHb[((size_t)(c * 256 + s0 + rl)) * 256 + col0 + nl];
    }
    f32x4 acc[2][2] = {};
    const ushort* ap0 = g16 + (size_t)(row0 + wm * 32 + lm) * DD + lk;
    const ushort* bp0 = WT16 + ((size_t)ch * 256 + col0 + wn * 32 + lm) * DD + lk;
#pragma unroll 4
    for (int k0 = 0; k0 < DD; k0 += 32) {
      bf16x8 a0 = *(const bf16x8*)(ap0 + k0);
      bf16x8 a1 = *(const bf16x8*)(ap0 + 16 * DD + k0);
      bf16x8 b0 = *(const bf16x8*)(bp0 + k0);
      bf16x8 b1 = *(const bf16x8*)(bp0 + 16 * DD + k0);
      acc[0][0] = __builtin_amdgcn_mfma_f32_16x16x32_bf16(a0, b0, acc[0][0], 0, 0, 0);
      acc[0][1] = __builtin_amdgcn_mfma_f32_16x16x32_bf16(a0, b1, acc[0][1], 0, 0, 0);
      acc[1][0] = __builtin_amdgcn_mfma_f32_16x16x32_bf16(a1, b0, acc[1][0], 0, 0, 0);
      acc[1][1] = __builtin_amdgcn_mfma_f32_16x16x32_bf16(a1, b1, acc[1][1], 0, 0, 0);
    }
    __syncthreads();
#pragma unroll
    for (int i = 0; i < 2; i++)
#pragma unroll
      for (int jj = 0; jj < 2; jj++)
#pragma unroll
        for (int r = 0; r < 4; r++) {
          int rm = wm * 32 + i * 16 + (l >> 4) * 4 + r;
          int cn = wn * 32 + jj * 16 + lm;
          float vo = acc[i][jj][r] + ehs[rm][cn];
          Fb16[((size_t)ch * 2048 + row0 + rm) * 256 + col0 + cn] = f2bf(vo);
        }
  } else {
    // ---- zpart ----
    int i = blk - 512;
    int chunk = i % 6, path = (i / 6) & 1, b = i / 12;
    int rg = t >> 6, ct = t & 63;
    float* sf = sm;
    float (*red)[256] = reinterpret_cast<float(*)[256]>(sm + 128);
    if (t < 128) sf[t] = fg[b * DD + chunk * 128 + t];
    __syncthreads();
    const float* W = (path ? lsW1 : muW1) + (size_t)(chunk * 128) * 256;
    float acc[4] = {0.f, 0.f, 0.f, 0.f};
#pragma unroll 4
    for (int it = 0; it < 32; it++) {
      int d = it * 4 + rg;
      float f = sf[d];
      float4 w = *reinterpret_cast<const float4*>(W + (size_t)d * 256 + ct * 4);
      acc[0] = fmaf(f, w.x, acc[0]);
      acc[1] = fmaf(f, w.y, acc[1]);
      acc[2] = fmaf(f, w.z, acc[2]);
      acc[3] = fmaf(f, w.w, acc[3]);
    }
    *reinterpret_cast<float4*>(&red[rg][ct * 4]) =
        make_float4(acc[0], acc[1], acc[2], acc[3]);
    __syncthreads();
    zscr[(((size_t)(b * 2 + path)) * 6 + chunk) * 256 + t] =
        red[0][t] + red[1][t] + red[2][t] + red[3][t];
  }
}

// ============ k_pair: pairmlp(768) | zfinish(8) | A-identity fill ============
__global__ void __launch_bounds__(256) k_pair(const ushort* __restrict__ Fb16,
    const ushort* __restrict__ W2T16, const float* __restrict__ b2,
    const float* __restrict__ W3, const float* __restrict__ b3,
    const float* __restrict__ zscr,
    const float* __restrict__ mub1, const float* __restrict__ muW2,
    const float* __restrict__ mub2,
    const float* __restrict__ lsb1, const float* __restrict__ lsW2,
    const float* __restrict__ lsb2, const float* __restrict__ eps,
    float* __restrict__ val,
    float* __restrict__ o_zmu, float* __restrict__ o_zls, float* __restrict__ o_zs,
    float* __restrict__ A) {
  __shared__ __align__(16) ushort h1s[64 * 256];
  __shared__ float psum2[2][64];
  int blk = blockIdx.x;
  int t = threadIdx.x;
  if (blk >= 776) {
    // ---- identity fill, rows [SCRATCH_ROWS+FILL_SPLIT, 16384) ----
    int r_g = SCRATCH_ROWS + FILL_SPLIT + (blk - 776);
    if (!row_sampled(r_g & 1023)) identity_row(A, r_g, t);
    return;
  }
  if (blk < 768) {
    // ---- pairmlp ----
    int bc = blk / 48, grp = blk - bc * 48;
    int b = bc >> 1, c = bc & 1;
    int wid = t >> 6, l = t & 63;
    int wm = wid & 1, wn = wid >> 1;
    int lm = l & 15, lk = (l >> 4) * 8;
    {
      int p_l = t >> 2, q = t & 3;
      int j = grp * 64 + p_l;
      int s = j / 12, ko = j - s * 12;
      int u = s >> 4, v = s & 15;
      int ub = u + c_du[ko], vb = v + c_dv[ko];
      bool vld = (ub >= 0) && (ub < 16) && (vb >= 0) && (vb < 16);
      int sb = vld ? ub * 16 + vb : s;
      const ushort* f1p = Fb16 + ((size_t)(c * 2048 + b * 256 + s)) * 256 + q * 64;
      const ushort* f2p = Fb16 + ((size_t)((2 + c) * 2048 + b * 256 + sb)) * 256 + q * 64;
      char* hb = (char*)h1s;
#pragma unroll
      for (int kk = 0; kk < 64; kk += 8) {
        bf16x8 x1 = *(const bf16x8*)(f1p + kk);
        bf16x8 x2 = *(const bf16x8*)(f2p + kk);
        bf16x8 o;
#pragma unroll
        for (int e = 0; e < 8; e++) {
          float a = bf2f((ushort)x1[e]) + bf2f((ushort)x2[e]);
          o[e] = (short)f2bf(fmaxf(a, 0.f));
        }
        int byt = (p_l * 512 + (q * 64 + kk) * 2) ^ ((p_l & 7) << 4);
        *(bf16x8*)(hb + byt) = o;
      }
    }
    __syncthreads();
    f32x4 acc[2][4] = {};
    const ushort* wp = W2T16 + ((size_t)(c * 128 + wn * 64 + lm)) * 256 + lk;
    const char* hb = (const char*)h1s;
    int p0 = wm * 32 + lm;
    int swz = (p0 & 7) << 4;
#pragma unroll 2
    for (int k0 = 0; k0 < 256; k0 += 32) {
      bf16x8 a0 = *(const bf16x8*)(hb + ((p0 * 512 + (k0 + lk) * 2) ^ swz));
      bf16x8 a1 = *(const bf16x8*)(hb + (((p0 + 16) * 512 + (k0 + lk) * 2) ^ swz));
#pragma unroll
      for (int nf = 0; nf < 4; nf++) {
        bf16x8 bb = *(const bf16x8*)(wp + nf * 16 * 256 + k0);
        acc[0][nf] = __builtin_amdgcn_mfma_f32_16x16x32_bf16(a0, bb, acc[0][nf], 0, 0, 0);
        acc[1][nf] = __builtin_amdgcn_mfma_f32_16x16x32_bf16(a1, bb, acc[1][nf], 0, 0, 0);
      }
    }
    float b2v[4], w3v[4];
#pragma unroll
    for (int nf = 0; nf < 4; nf++) {
      int col = wn * 64 + nf * 16 + lm;
      b2v[nf] = b2[c * 128 + col];
      w3v[nf] = W3[c * 128 + col];
    }
    float part[2][4];
#pragma unroll
    for (int mf = 0; mf < 2; mf++)
#pragma unroll
      for (int r = 0; r < 4; r++) {
        float ssum = 0.f;
#pragma unroll
        for (int nf = 0; nf < 4; nf++) {
          float h = fmaxf(acc[mf][nf][r] + b2v[nf], 0.f);
          ssum = fmaf(h, w3v[nf], ssum);
        }
        part[mf][r] = ssum;
      }
#pragma unroll
    for (int m = 1; m <= 8; m <<= 1)
#pragma unroll
      for (int mf = 0; mf < 2; mf++)
#pragma unroll
        for (int r = 0; r < 4; r++)
          part[mf][r] += __shfl_xor(part[mf][r], m, 64);
    if (lm == 0) {
#pragma unroll
      for (int mf = 0; mf < 2; mf++)
#pragma unroll
        for (int r = 0; r < 4; r++)
          psum2[wn][wm * 32 + mf * 16 + (l >> 4) * 4 + r] = part[mf][r];
    }
    __syncthreads();
    if (t < 64) {
      int jj = grp * 64 + t;
      int ss = jj / 12, kk2 = jj - ss * 12;
      int uu = ss >> 4, vv2 = ss & 15;
      int ub2 = uu + c_du[kk2], vb2 = vv2 + c_dv[kk2];
      bool vld = (ub2 >= 0) && (ub2 < 16) && (vb2 >= 0) && (vb2 < 16);
      float lg = psum2[0][t] + psum2[1][t] + b3[c];
      float sv = 1.0f / (1.0f + expf(-lg));
      val[(size_t)bc * PPAD + jj] = vld ? sv : 0.0f;
    }
  } else {
    // ---- zfinish ----
    int b = blk - 768;
    float* shm = (float*)h1s;
    float* shl = shm + 256;
    float* zres = shm + 512;
    float hm = mub1[t], hl = lsb1[t];
#pragma unroll
    for (int ch = 0; ch < 6; ch++) {
      hm += zscr[(((size_t)(b * 2 + 0)) * 6 + ch) * 256 + t];
      hl += zscr[(((size_t)(b * 2 + 1)) * 6 + ch) * 256 + t];
    }
    shm[t] = fmaxf(hm, 0.f);
    shl[t] = fmaxf(hl, 0.f);
    __syncthreads();
    if (t < 128 && (t & 63) < 8) {
      int path = t >> 6, kk = t & 7;
      const float* W2p = path ? lsW2 : muW2;
      const float* bi = path ? lsb2 : mub2;
      const float* sh = path ? shl : shm;
      float z = bi[kk];
      for (int i = 0; i < 256; i++) z = fmaf(sh[i], W2p[i * 8 + kk], z);
      zres[path * 8 + kk] = z;
    }
    __syncthreads();
    if (t < 8) {
      float zm = zres[t], zl = zres[8 + t];
      o_zmu[b * 8 + t] = zm;
      o_zls[b * 8 + t] = zl;
      o_zs[b * 8 + t] = zm + expf(zl) * eps[b * 8 + t];
    }
  }
}

// ============ k_final: sampled rows(4096) | early rows(2366) | diffuse(16) ============
__global__ void __launch_bounds__(256) k_final(const float* __restrict__ val,
    const float* __restrict__ cam,
    const float* __restrict__ csc, const float* __restrict__ cbi,
    float* __restrict__ A, float* __restrict__ o_cam, float* __restrict__ o_conf) {
  __shared__ float smf[260];
  int blk = blockIdx.x;
  int t = threadIdx.x;
  if (blk < 4096) {
    // ---- sampled-site rows ----
    int bc = blk >> 8, s = blk & 255;
    int u = s >> 4, v = s & 15;
    int row = u * 64 + 2 * v;
    size_t base = (size_t)bc * HWN * HWN + (size_t)row * HWN;
    float* sv = smf;
    if (t < 12) sv[t] = val[(size_t)bc * PPAD + s * 12 + t];
    __syncthreads();
    if (t == 0) {
      float ssum = 1.f;
      for (int k = 0; k < 12; k++) ssum += sv[k];
      smf[12] = 1.f / (ssum + 1e-8f);
    }
    __syncthreads();
    float inv = smf[12];
    float vo[4];
#pragma unroll
    for (int e = 0; e < 4; e++) {
      int col = t * 4 + e;
      float x = 0.f;
      if (col == row) {
        x = inv;
      } else if ((col & 33) == 0) {
        int cu = col >> 6, cv = (col & 31) >> 1;
        int du = cu - u + 2, dv = cv - v + 2;
        if (((unsigned)du < 5u) && ((unsigned)dv < 5u)) {
          int k = c_rk[du * 5 + dv];
          if (k >= 0) x = sv[k] * inv;
        }
      }
      vo[e] = x;
    }
    reinterpret_cast<float4*>(A + base)[t] =
        make_float4(vo[0], vo[1], vo[2], vo[3]);
  } else if (blk < 4096 + SCRATCH_ROWS) {
    // ---- early rows (former scratch region): identity for non-sampled ----
    int r_g = blk - 4096;
    if (!row_sampled(r_g & 1023)) identity_row(A, r_g, t);
  } else {
    // ---- diffuse ----
    int bc = blk - (4096 + SCRATCH_ROWS);
    float* M = smf;
    int u = t >> 4, v = t & 15;
    int pix = (u << 6) + (v << 1);
    const float* camr = cam + (size_t)bc * HWN;
    float m = camr[pix];
    float vv[12];
    int nb[12];
    float ssum = 1.f;
#pragma unroll
    for (int k = 0; k < 12; k++) {
      int ub = u + c_du[k], vb = v + c_dv[k];
      bool vld = (ub >= 0) && (ub < 16) && (vb >= 0) && (vb < 16);
      nb[k] = vld ? ub * 16 + vb : t;
      vv[k] = vld ? val[(size_t)bc * PPAD + t * 12 + k] : 0.0f;
      ssum += vv[k];
    }
    float inv = 1.0f / (ssum + 1e-8f);
    float degn = ssum * inv;
    M[t] = m;
    __syncthreads();
    for (int step = 0; step < 3; step++) {
      float accv = m;
#pragma unroll
      for (int k = 0; k < 12; k++) accv = fmaf(vv[k], M[nb[k]], accv);
      float L = accv * inv - degn * m;
      m = fmaf(0.1f, L, m);
      __syncthreads();
      M[t] = m;
      __syncthreads();
    }
    float scale = csc[0], bias = cbi[0];
    for (int p = t; p < HWN; p += 256) {
      int ppi = p >> 5, ppj = p & 31;
      float x;
      if (((ppi | ppj) & 1) == 0) x = M[(ppi >> 1) * 16 + (ppj >> 1)];
      else x = camr[p];
      x = fminf(fmaxf(x, 0.0f), 1.0f);
      o_cam[(size_t)bc * HWN + p] = x;
      o_conf[(size_t)bc * HWN + p] = 1.0f / (1.0f + expf(-(scale * x + bias)));
    }
  }
}

extern "C" void kernel_launch(void* const* d_in, const int* in_sizes, int n_in,
                              void* d_out, int out_size, void* d_ws, size_t ws_size,
                              hipStream_t stream) {
  const float* feat = (const float*)d_in[0];
  const float* cam  = (const float*)d_in[1];
  const float* eps  = (const float*)d_in[3];
  const float* cemb = (const float*)d_in[4];
  const float* aW1  = (const float*)d_in[5];
  const float* ab1  = (const float*)d_in[6];
  const float* aW2  = (const float*)d_in[7];
  const float* ab2  = (const float*)d_in[8];
  const float* aW3  = (const float*)d_in[9];
  const float* ab3  = (const float*)d_in[10];
  const float* muW1 = (const float*)d_in[11];
  const float* mub1 = (const float*)d_in[12];
  const float* muW2 = (const float*)d_in[13];
  const float* mub2 = (const float*)d_in[14];
  const float* lsW1 = (const float*)d_in[15];
  const float* lsb1 = (const float*)d_in[16];
  const float* lsW2 = (const float*)d_in[17];
  const float* lsb2 = (const float*)d_in[18];
  const float* csc  = (const float*)d_in[19];
  const float* cbi  = (const float*)d_in[20];

  float* out = (float*)d_out;
  float* o_cam  = out;                       // 16384
  float* o_zmu  = out + 16384;               // 64
  float* o_zls  = out + 16448;               // 64
  float* o_zs   = out + 16512;               // 64
  float* o_A    = out + 16576;               // 16777216
  float* o_conf = out + 16793792;            // 16384

  // scratch aliased into the A region (rows < 2366); only val in d_ws
  float*  fg    = o_A;                                   // 6144 f32
  float*  EHb   = o_A + 6144;                            // 131072 f32
  ushort* g16   = (ushort*)(o_A + 137216);               // 2048*768 bf16
  ushort* WT16  = (ushort*)(o_A + 923648);               // 4*256*768 bf16
  ushort* W2T16 = (ushort*)(o_A + 1316864);              // 2*128*256 bf16
  ushort* Fb16  = (ushort*)(o_A + 1349632);              // 4*2048*256 bf16
  float*  zscr  = o_A + 2398208;                         // ends @2422784 = row 2366
  float*  valb  = (float*)d_ws;                          // 16*3072 f32

  hipLaunchKernelGGL(k_pre, dim3(6864), dim3(256), 0, stream,
                     feat, cemb, aW1, ab1, aW2, fg, g16, EHb, WT16, W2T16);
  hipLaunchKernelGGL(k_mid, dim3(608 + FILL_SPLIT), dim3(256), 0, stream,
                     g16, WT16, EHb, fg, muW1, lsW1, Fb16, zscr, o_A);
  hipLaunchKernelGGL(k_pair, dim3(776 + (16384 - SCRATCH_ROWS - FILL_SPLIT)),
                     dim3(256), 0, stream,
                     Fb16, W2T16, ab2, aW3, ab3, zscr,
                     mub1, muW2, mub2, lsb1, lsW2, lsb2, eps,
                     valb, o_zmu, o_zls, o_zs, o_A);
  hipLaunchKernelGGL(k_final, dim3(4096 + SCRATCH_ROWS + 16), dim3(256), 0, stream,
                     valb, cam, csc, cbi, o_A, o_cam, o_conf);
}